// Round 1
// baseline (9685.627 us; speedup 1.0000x reference)
//
#include <hip/hip_runtime.h>
#include <hip/hip_bf16.h>
#include <math.h>

#define H 1024
#define B 32
#define T 256
#define L 4
#define O 256
#define NJ 5          // projections j = 1..5 (k,v,i,f,o); q (j=0) is unused -> skipped
#define COLS 128
#define CHUNKS 8      // 1024 / COLS
#define KSPLIT 4
#define KLEN 256      // 1024 / KSPLIT
#define KT 32

// ws layout (floats):
//   cstate: L*B*H          = 131072   @ 0
//   nstate:                  131072   @ 131072
//   hbuf:   L*2*B*H        = 262144   @ 262144   (output of layer l at parity t&1)
//   zbuf:   KSPLIT*L*NJ*B*H= 2621440  @ 524288
// total = 3145728 floats = 12 MB

__global__ __launch_bounds__(256) void gemm_wf(
    const float* __restrict__ x, const float* __restrict__ W,
    const float* __restrict__ bias, const float* __restrict__ hbuf,
    float* __restrict__ zbuf, int dwf, int lmin) {
  // bi = ((cell*NJ + jj)*CHUNKS + chunk)*KSPLIT + kh
  int bi = blockIdx.x;
  int kh = bi & 3;
  int chunk = (bi >> 2) & 7;
  int jj = (bi >> 5) % NJ;
  int cell = bi / (NJ * CHUNKS * KSPLIT);
  int l = lmin + cell;
  int t = dwf - l;
  int j = jj + 1;

  const float* xin;
  int xstride;
  if (l == 0) { xin = x + (size_t)t * H; xstride = T * H; }
  else        { xin = hbuf + (size_t)((l - 1) * 2 + (t & 1)) * B * H; xstride = H; }
  const float* Wp = W + ((size_t)(l * 6 + j) << 20);  // 1024*1024 per (l,j)
  int c0 = chunk * COLS;
  int kbase = kh * KLEN;

  __shared__ float xs[B][KT + 4];        // 32 x 36 (pad, keeps 16B align)
  __shared__ float wsh[KT][COLS + 2];    // 32 x 130

  int tx = threadIdx.x & 63;
  int ty = threadIdx.x >> 6;

  float2 acc[8];
#pragma unroll
  for (int i = 0; i < 8; ++i) acc[i] = make_float2(0.f, 0.f);

  for (int k0 = kbase; k0 < kbase + KLEN; k0 += KT) {
    // stage x tile: 32 x 32 = 1024 elems, 4/thread
#pragma unroll
    for (int s = 0; s < 4; ++s) {
      int e = threadIdx.x + s * 256;
      int bb = e >> 5, kk = e & 31;
      xs[bb][kk] = xin[(size_t)bb * xstride + k0 + kk];
    }
    // stage W tile: 32 x 128 = 4096 elems, 16/thread
#pragma unroll
    for (int s = 0; s < 16; ++s) {
      int e = threadIdx.x + s * 256;
      int kk = e >> 7, dd = e & 127;
      wsh[kk][dd] = Wp[(size_t)(k0 + kk) * H + c0 + dd];
    }
    __syncthreads();
#pragma unroll
    for (int kk = 0; kk < KT; ++kk) {
      float2 w2 = *(const float2*)&wsh[kk][tx * 2];
#pragma unroll
      for (int i = 0; i < 8; ++i) {
        float xv = xs[ty * 8 + i][kk];
        acc[i].x = fmaf(xv, w2.x, acc[i].x);
        acc[i].y = fmaf(xv, w2.y, acc[i].y);
      }
    }
    __syncthreads();
  }

  float2 bv = make_float2(0.f, 0.f);
  if (kh == 0) {
    const float* bp = bias + (size_t)(l * 6 + j) * H + c0;
    bv = *(const float2*)&bp[tx * 2];
  }
  float* zp = zbuf + ((size_t)kh * L * NJ * B + (size_t)(l * NJ + jj) * B) * H;
#pragma unroll
  for (int i = 0; i < 8; ++i) {
    int bb = ty * 8 + i;
    float2 o2 = make_float2(acc[i].x + bv.x, acc[i].y + bv.y);
    *(float2*)&zp[(size_t)bb * H + c0 + tx * 2] = o2;
  }
}

__device__ __forceinline__ float2 breduce2(float a, float c, float* sb) {
#pragma unroll
  for (int off = 32; off > 0; off >>= 1) {
    a += __shfl_down(a, off, 64);
    c += __shfl_down(c, off, 64);
  }
  int w = threadIdx.x >> 6;
  if ((threadIdx.x & 63) == 0) { sb[w] = a; sb[w + 4] = c; }
  __syncthreads();
  float2 r = make_float2(sb[0] + sb[1] + sb[2] + sb[3],
                         sb[4] + sb[5] + sb[6] + sb[7]);
  __syncthreads();
  return r;
}

__global__ __launch_bounds__(256) void cell_update(
    const float* __restrict__ zbuf, const float* __restrict__ ln_g,
    const float* __restrict__ ln_b, float* __restrict__ cstate,
    float* __restrict__ nstate, float* __restrict__ hbuf,
    int dwf, int lmin) {
  int cell = blockIdx.x >> 5;
  int b = blockIdx.x & 31;
  int l = lmin + cell;
  int t = dwf - l;
  int tid = threadIdx.x;
  __shared__ float sb[8];

  const size_t kstride = (size_t)L * NJ * B * H;
  float vals[5][4];
#pragma unroll
  for (int jj = 0; jj < NJ; ++jj) {
    size_t zoff = ((size_t)(l * NJ + jj) * B + b) * H + tid * 4;
    float4 v  = *(const float4*)&zbuf[zoff];
    float4 v1 = *(const float4*)&zbuf[zoff + kstride];
    float4 v2 = *(const float4*)&zbuf[zoff + 2 * kstride];
    float4 v3 = *(const float4*)&zbuf[zoff + 3 * kstride];
    v.x += v1.x + v2.x + v3.x;
    v.y += v1.y + v2.y + v3.y;
    v.z += v1.z + v2.z + v3.z;
    v.w += v1.w + v2.w + v3.w;
    float s  = v.x + v.y + v.z + v.w;
    float sq = v.x * v.x + v.y * v.y + v.z * v.z + v.w * v.w;
    float2 r = breduce2(s, sq, sb);
    float mu = r.x * (1.0f / H);
    float var = r.y * (1.0f / H) - mu * mu;
    float rs = rsqrtf(var + 1e-5f);
    int j = jj + 1;
    float4 g  = *(const float4*)&ln_g[(size_t)(l * 6 + j) * H + tid * 4];
    float4 be = *(const float4*)&ln_b[(size_t)(l * 6 + j) * H + tid * 4];
    vals[jj][0] = (v.x - mu) * rs * g.x + be.x;
    vals[jj][1] = (v.y - mu) * rs * g.y + be.y;
    vals[jj][2] = (v.z - mu) * rs * g.z + be.z;
    vals[jj][3] = (v.w - mu) * rs * g.w + be.w;
  }
  // vals: 0=k, 1=v, 2=zi, 3=zf, 4=zo
  float* crow = cstate + ((size_t)l * B + b) * H;
  float* nrow = nstate + ((size_t)l * B + b) * H;
  float4 cp = *(const float4*)&crow[tid * 4];
  float4 np = *(const float4*)&nrow[tid * 4];
  float cpv[4] = {cp.x, cp.y, cp.z, cp.w};
  float npv[4] = {np.x, np.y, np.z, np.w};

  float iv[4], fv[4], ov[4], nnew[4], cnew[4];
#pragma unroll
  for (int u = 0; u < 4; ++u) {
    iv[u] = expf(vals[2][u]);
    fv[u] = 1.f / (1.f + expf(-vals[3][u]));
    ov[u] = 1.f / (1.f + expf(-vals[4][u]));
  }
  float ksl = vals[0][0] + vals[0][1] + vals[0][2] + vals[0][3];
  float nsl = 0.f;
#pragma unroll
  for (int u = 0; u < 4; ++u) {
    nnew[u] = fv[u] * npv[u] + iv[u] * vals[0][u];
    nsl += nnew[u] * nnew[u];
  }
  float2 r2 = breduce2(ksl, nsl, sb);
  float ksum = r2.x;
  float rn = 1.f / (sqrtf(r2.y) + 1e-8f);

  float rvv[4] = {0.f, 0.f, 0.f, 0.f};
  if (l > 0) {
    const float* resid = hbuf + ((size_t)((l - 1) * 2 + (t & 1)) * B + b) * H;
    float4 rv = *(const float4*)&resid[tid * 4];
    rvv[0] = rv.x; rvv[1] = rv.y; rvv[2] = rv.z; rvv[3] = rv.w;
  }
  float hh[4];
#pragma unroll
  for (int u = 0; u < 4; ++u) {
    cnew[u] = fv[u] * cpv[u] + iv[u] * (ksum * vals[1][u]);
    hh[u] = ov[u] * tanhf(cnew[u] * (nnew[u] * rn)) + rvv[u];
  }
  *(float4*)&crow[tid * 4] = make_float4(cnew[0], cnew[1], cnew[2], cnew[3]);
  *(float4*)&nrow[tid * 4] = make_float4(nnew[0], nnew[1], nnew[2], nnew[3]);
  float* hout = hbuf + ((size_t)(l * 2 + (t & 1)) * B + b) * H;
  *(float4*)&hout[tid * 4] = make_float4(hh[0], hh[1], hh[2], hh[3]);
}

__global__ __launch_bounds__(256) void fc_kernel(
    const float* __restrict__ hbuf, const float* __restrict__ fc_w,
    const float* __restrict__ fc_b, float* __restrict__ out) {
  int b = blockIdx.x;
  int o = threadIdx.x;
  const float* hr = hbuf + ((size_t)(3 * 2 + 1) * B + b) * H;
  float acc = fc_b[o];
#pragma unroll 4
  for (int h = 0; h < H; ++h)
    acc = fmaf(hr[h], fc_w[(size_t)h * O + o], acc);
  out[(size_t)b * O + o] = acc;
}

__global__ __launch_bounds__(256) void finalize_copy(
    const float* __restrict__ hbuf, const float* __restrict__ cstate,
    const float* __restrict__ nstate, float* __restrict__ out) {
  int i = blockIdx.x * 256 + threadIdx.x;  // 0..131071
  int l = i >> 15;
  int r = i & 32767;
  out[8192 + i]          = hbuf[(size_t)(l * 2 + 1) * B * H + r];
  out[8192 + 131072 + i] = cstate[i];
  out[8192 + 262144 + i] = nstate[i];
}

extern "C" void kernel_launch(void* const* d_in, const int* in_sizes, int n_in,
                              void* d_out, int out_size, void* d_ws, size_t ws_size,
                              hipStream_t stream) {
  const float* x    = (const float*)d_in[0];
  const float* W    = (const float*)d_in[1];
  const float* bias = (const float*)d_in[2];
  const float* ln_g = (const float*)d_in[3];
  const float* ln_b = (const float*)d_in[4];
  const float* fc_w = (const float*)d_in[5];
  const float* fc_b = (const float*)d_in[6];
  float* out = (float*)d_out;
  float* ws = (float*)d_ws;

  float* cstate = ws;
  float* nstate = ws + 131072;
  float* hbuf   = ws + 262144;
  float* zbuf   = ws + 524288;

  hipMemsetAsync(ws, 0, 262144 * sizeof(float), stream);

  for (int d = 0; d < T + L - 1; ++d) {
    int lmin = (d > T - 1) ? d - (T - 1) : 0;
    int lmax = (d < L - 1) ? d : L - 1;
    int nc = lmax - lmin + 1;
    gemm_wf<<<nc * NJ * CHUNKS * KSPLIT, 256, 0, stream>>>(
        x, W, bias, hbuf, zbuf, d, lmin);
    cell_update<<<nc * B, 256, 0, stream>>>(
        zbuf, ln_g, ln_b, cstate, nstate, hbuf, d, lmin);
  }
  fc_kernel<<<B, 256, 0, stream>>>(hbuf, fc_w, fc_b, out);
  finalize_copy<<<131072 / 256, 256, 0, stream>>>(hbuf, cstate, nstate, out);
}

// Round 2
// 4609.634 us; speedup vs baseline: 2.1012x; 2.1012x over previous
//
#include <hip/hip_runtime.h>
#include <hip/hip_bf16.h>
#include <math.h>

#define H 1024
#define B 32
#define T 256
#define L 4
#define O 256
#define NJ 5   // projections j=1..5 (k,v,i,f,o); q (j=0) unused -> skipped

typedef _Float16 half8 __attribute__((ext_vector_type(8)));
typedef _Float16 half4 __attribute__((ext_vector_type(4)));
typedef float f32x4 __attribute__((ext_vector_type(4)));

// ws layout (float offsets):
//   cstate: 131072 f32 @ 0
//   nstate: 131072 f32 @ 131072
//   hbuf:   262144 f32 @ 262144   (L*2*B*H, parity-double-buffered h, fp32)
//   zbuf:   655360 f32 @ 524288   (L*NJ*B*H)
//   f16 area @ float-offset 1179648:
//     h_swz: L*2*32768 halves  (A-frag layout per (layer,parity))
//     x_swz: T*32768 halves
//     Wt2:   20*1048576 halves (B-frag layout, fragment-contiguous)
// total ~61 MB

// ---- pack W[l][j][k][n] fp32 -> Wt2 f16, B-frag layout:
// off(m_idx, nt, ks, lane, e) = m_idx*2^20 + (nt*32+ks)*512 + lane*8 + e
// value = W[k= ks*32+(lane>>4)*8+e][n= nt*16+(lane&15)]
__global__ __launch_bounds__(256) void pack_w(const float* __restrict__ W,
                                              _Float16* __restrict__ Wt2) {
  int tile = blockIdx.x;
  int m_idx = tile >> 8;            // 0..19  (= l*5+jj)
  int kt = (tile >> 4) & 15, ntt = tile & 15;
  int l = m_idx / 5, jj = m_idx % 5;
  const float* Wf = W + ((size_t)(l * 6 + jj + 1) << 20);
  _Float16* out = Wt2 + ((size_t)m_idx << 20);
  __shared__ float ts[64][65];
  int k0 = kt * 64, n0 = ntt * 64;
#pragma unroll
  for (int s = 0; s < 16; ++s) {
    int e = threadIdx.x + s * 256;
    int kk = e >> 6, col = e & 63;
    ts[kk][col] = Wf[(size_t)(k0 + kk) * H + n0 + col];
  }
  __syncthreads();
#pragma unroll
  for (int gi = 0; gi < 2; ++gi) {
    int g = threadIdx.x * 2 + gi;   // 0..511
    int l64 = g & 63, ksl = (g >> 6) & 1, ntl = g >> 7;
    int nn = l64 & 15, kh = l64 >> 4;
    half8 tmp;
#pragma unroll
    for (int e = 0; e < 8; ++e)
      tmp[e] = (_Float16)ts[ksl * 32 + kh * 8 + e][ntl * 16 + nn];
    *(half8*)&out[(size_t)((ntt * 4 + ntl) * 32 + kt * 2 + ksl) * 512 + (size_t)l64 * 8] = tmp;
  }
}

// ---- pack x[b][t][k] fp32 -> x_swz f16 A-frag layout per t:
// off(t, bt, ks, lane, e) = t*32768 + bt*16384 + ks*512 + lane*8 + e
// value = x[b= bt*16+(lane&15)][t][k= ks*32+(lane>>4)*8+e]
__global__ __launch_bounds__(256) void pack_x(const float* __restrict__ x,
                                              _Float16* __restrict__ x_swz) {
  int t = blockIdx.x;
  __shared__ float ld[32][257];
  for (int c = 0; c < 4; ++c) {
#pragma unroll
    for (int s = 0; s < 32; ++s) {
      int e2 = threadIdx.x + s * 256;
      int b = e2 >> 8, col = e2 & 255;
      ld[b][col] = x[((size_t)b * T + t) * H + c * 256 + col];
    }
    __syncthreads();
#pragma unroll
    for (int s3 = 0; s3 < 4; ++s3) {
      int gg = threadIdx.x * 4 + s3;  // 0..1023
      int l64 = gg & 63, ksl = (gg >> 6) & 7, bt = gg >> 9;
      int nn = l64 & 15, kh = l64 >> 4;
      int b = bt * 16 + nn;
      half8 tmp;
#pragma unroll
      for (int e = 0; e < 8; ++e)
        tmp[e] = (_Float16)ld[b][ksl * 32 + kh * 8 + e];
      *(half8*)&x_swz[(size_t)t * 32768 + bt * 16384 +
                      (size_t)(c * 8 + ksl) * 512 + (size_t)l64 * 8] = tmp;
    }
    __syncthreads();
  }
}

// ---- MFMA GEMM: z[l][jj][b][n] = sum_k A[b][k] * W[k][n]
// block: 512 thr / 8 waves; tile 32(m) x 32(n); wave w owns k-range [w*128, w*128+128)
// grid: nc * NJ * 32
__global__ __launch_bounds__(512, 4) void gemm_mfma(
    const _Float16* __restrict__ x_swz, const _Float16* __restrict__ h_swz,
    const _Float16* __restrict__ Wt2, float* __restrict__ zbuf,
    int dwf, int lmin) {
  int bi = blockIdx.x;
  int ch = bi & 31;
  int jj = (bi >> 5) % 5;
  int cell = bi / 160;
  int l = lmin + cell, t = dwf - l;
  const _Float16* A = (l == 0) ? x_swz + (size_t)t * 32768
                               : h_swz + (size_t)((l - 1) * 2 + (t & 1)) * 32768;
  const _Float16* Bw = Wt2 + ((size_t)(l * 5 + jj) << 20);
  int w = threadIdx.x >> 6, lane = threadIdx.x & 63;

  f32x4 acc[2][2] = {};
  const _Float16* pa0 = A + (size_t)(w * 4) * 512 + lane * 8;        // bt=0
  const _Float16* pa1 = pa0 + 16384;                                  // bt=1
  const _Float16* pb0 = Bw + (size_t)((ch * 2) * 32 + w * 4) * 512 + lane * 8;
  const _Float16* pb1 = pb0 + 16384;                                  // nt+1

  half8 a0[4], a1[4], b0[4], b1[4];
#pragma unroll
  for (int s = 0; s < 4; ++s) {
    a0[s] = *(const half8*)(pa0 + s * 512);
    a1[s] = *(const half8*)(pa1 + s * 512);
    b0[s] = *(const half8*)(pb0 + s * 512);
    b1[s] = *(const half8*)(pb1 + s * 512);
  }
#pragma unroll
  for (int s = 0; s < 4; ++s) {
    acc[0][0] = __builtin_amdgcn_mfma_f32_16x16x32_f16(a0[s], b0[s], acc[0][0], 0, 0, 0);
    acc[0][1] = __builtin_amdgcn_mfma_f32_16x16x32_f16(a0[s], b1[s], acc[0][1], 0, 0, 0);
    acc[1][0] = __builtin_amdgcn_mfma_f32_16x16x32_f16(a1[s], b0[s], acc[1][0], 0, 0, 0);
    acc[1][1] = __builtin_amdgcn_mfma_f32_16x16x32_f16(a1[s], b1[s], acc[1][1], 0, 0, 0);
  }

  __shared__ float red[8192];  // 8 waves x 4 frags x 256
#pragma unroll
  for (int bt = 0; bt < 2; ++bt)
#pragma unroll
    for (int ntl = 0; ntl < 2; ++ntl)
      *(f32x4*)&red[(size_t)(w * 4 + bt * 2 + ntl) * 256 + lane * 4] = acc[bt][ntl];
  __syncthreads();

  float* zp = zbuf + ((size_t)(l * 5 + jj) * 32) * 1024 + ch * 32;
#pragma unroll
  for (int i = 0; i < 2; ++i) {
    int o = threadIdx.x * 2 + i;
    int m = o >> 5, n = o & 31;
    int idx = ((m >> 4) * 2 + (n >> 4)) * 256 + (((m & 15) >> 2) * 16 + (n & 15)) * 4 + (m & 3);
    float s = 0.f;
#pragma unroll
    for (int ww = 0; ww < 8; ++ww) s += red[ww * 1024 + idx];
    zp[(size_t)m * 1024 + n] = s;
  }
}

__device__ __forceinline__ float2 breduce2(float a, float c, float* sb) {
#pragma unroll
  for (int off = 32; off > 0; off >>= 1) {
    a += __shfl_down(a, off, 64);
    c += __shfl_down(c, off, 64);
  }
  int w = threadIdx.x >> 6;
  if ((threadIdx.x & 63) == 0) { sb[w] = a; sb[w + 4] = c; }
  __syncthreads();
  float2 r = make_float2(sb[0] + sb[1] + sb[2] + sb[3],
                         sb[4] + sb[5] + sb[6] + sb[7]);
  __syncthreads();
  return r;
}

__global__ __launch_bounds__(256) void cell_update(
    const float* __restrict__ zbuf, const float* __restrict__ bias,
    const float* __restrict__ ln_g, const float* __restrict__ ln_b,
    float* __restrict__ cstate, float* __restrict__ nstate,
    float* __restrict__ hbuf, _Float16* __restrict__ h_swz,
    int dwf, int lmin) {
  int cell = blockIdx.x >> 5;
  int b = blockIdx.x & 31;
  int l = lmin + cell;
  int t = dwf - l;
  int tid = threadIdx.x;
  __shared__ float sb[8];

  float vals[5][4];
#pragma unroll
  for (int jj = 0; jj < NJ; ++jj) {
    int j = jj + 1;
    size_t zoff = ((size_t)(l * NJ + jj) * B + b) * H + tid * 4;
    float4 v = *(const float4*)&zbuf[zoff];
    float4 bb = *(const float4*)&bias[(size_t)(l * 6 + j) * H + tid * 4];
    v.x += bb.x; v.y += bb.y; v.z += bb.z; v.w += bb.w;
    float s = v.x + v.y + v.z + v.w;
    float sq = v.x * v.x + v.y * v.y + v.z * v.z + v.w * v.w;
    float2 r = breduce2(s, sq, sb);
    float mu = r.x * (1.0f / H);
    float var = r.y * (1.0f / H) - mu * mu;
    float rs = rsqrtf(var + 1e-5f);
    float4 g = *(const float4*)&ln_g[(size_t)(l * 6 + j) * H + tid * 4];
    float4 be = *(const float4*)&ln_b[(size_t)(l * 6 + j) * H + tid * 4];
    vals[jj][0] = (v.x - mu) * rs * g.x + be.x;
    vals[jj][1] = (v.y - mu) * rs * g.y + be.y;
    vals[jj][2] = (v.z - mu) * rs * g.z + be.z;
    vals[jj][3] = (v.w - mu) * rs * g.w + be.w;
  }
  // vals: 0=k, 1=v, 2=zi, 3=zf, 4=zo
  float* crow = cstate + ((size_t)l * B + b) * H;
  float* nrow = nstate + ((size_t)l * B + b) * H;
  float4 cp = *(const float4*)&crow[tid * 4];
  float4 np = *(const float4*)&nrow[tid * 4];
  float cpv[4] = {cp.x, cp.y, cp.z, cp.w};
  float npv[4] = {np.x, np.y, np.z, np.w};

  float iv[4], fv[4], ov[4], nnew[4], cnew[4];
#pragma unroll
  for (int u = 0; u < 4; ++u) {
    iv[u] = expf(vals[2][u]);
    fv[u] = 1.f / (1.f + expf(-vals[3][u]));
    ov[u] = 1.f / (1.f + expf(-vals[4][u]));
  }
  float ksl = vals[0][0] + vals[0][1] + vals[0][2] + vals[0][3];
  float nsl = 0.f;
#pragma unroll
  for (int u = 0; u < 4; ++u) {
    nnew[u] = fv[u] * npv[u] + iv[u] * vals[0][u];
    nsl += nnew[u] * nnew[u];
  }
  float2 r2 = breduce2(ksl, nsl, sb);
  float ksum = r2.x;
  float rn = 1.f / (sqrtf(r2.y) + 1e-8f);

  float rvv[4] = {0.f, 0.f, 0.f, 0.f};
  if (l > 0) {
    const float* resid = hbuf + ((size_t)((l - 1) * 2 + (t & 1)) * B + b) * H;
    float4 rv = *(const float4*)&resid[tid * 4];
    rvv[0] = rv.x; rvv[1] = rv.y; rvv[2] = rv.z; rvv[3] = rv.w;
  }
  float hh[4];
#pragma unroll
  for (int u = 0; u < 4; ++u) {
    cnew[u] = fv[u] * cpv[u] + iv[u] * (ksum * vals[1][u]);
    hh[u] = ov[u] * tanhf(cnew[u] * (nnew[u] * rn)) + rvv[u];
  }
  *(float4*)&crow[tid * 4] = make_float4(cnew[0], cnew[1], cnew[2], cnew[3]);
  *(float4*)&nrow[tid * 4] = make_float4(nnew[0], nnew[1], nnew[2], nnew[3]);
  float* hout = hbuf + ((size_t)(l * 2 + (t & 1)) * B + b) * H;
  *(float4*)&hout[tid * 4] = make_float4(hh[0], hh[1], hh[2], hh[3]);

  if (l < 3) {
    // write next layer's A-frag f16 copy
    int k0 = tid * 4;
    int ks = k0 >> 5, kk0 = k0 & 31;
    int bt = b >> 4, nn = b & 15;
    size_t off = (size_t)(l * 2 + (t & 1)) * 32768 + (size_t)bt * 16384 +
                 (size_t)ks * 512 + (size_t)((kk0 >> 3) * 16 + nn) * 8 + (kk0 & 7);
    half4 hx;
    hx[0] = (_Float16)hh[0]; hx[1] = (_Float16)hh[1];
    hx[2] = (_Float16)hh[2]; hx[3] = (_Float16)hh[3];
    *(half4*)&h_swz[off] = hx;
  }
}

__global__ __launch_bounds__(256) void fc_kernel(
    const float* __restrict__ hbuf, const float* __restrict__ fc_w,
    const float* __restrict__ fc_b, float* __restrict__ out) {
  int b = blockIdx.x;
  int o = threadIdx.x;
  const float* hr = hbuf + ((size_t)(3 * 2 + 1) * B + b) * H;
  float acc = fc_b[o];
#pragma unroll 4
  for (int h = 0; h < H; ++h)
    acc = fmaf(hr[h], fc_w[(size_t)h * O + o], acc);
  out[(size_t)b * O + o] = acc;
}

__global__ __launch_bounds__(256) void finalize_copy(
    const float* __restrict__ hbuf, const float* __restrict__ cstate,
    const float* __restrict__ nstate, float* __restrict__ out) {
  int i = blockIdx.x * 256 + threadIdx.x;  // 0..131071
  int l = i >> 15;
  int r = i & 32767;
  out[8192 + i]          = hbuf[(size_t)(l * 2 + 1) * B * H + r];
  out[8192 + 131072 + i] = cstate[i];
  out[8192 + 262144 + i] = nstate[i];
}

extern "C" void kernel_launch(void* const* d_in, const int* in_sizes, int n_in,
                              void* d_out, int out_size, void* d_ws, size_t ws_size,
                              hipStream_t stream) {
  const float* x    = (const float*)d_in[0];
  const float* W    = (const float*)d_in[1];
  const float* bias = (const float*)d_in[2];
  const float* ln_g = (const float*)d_in[3];
  const float* ln_b = (const float*)d_in[4];
  const float* fc_w = (const float*)d_in[5];
  const float* fc_b = (const float*)d_in[6];
  float* out = (float*)d_out;
  float* ws = (float*)d_ws;

  float* cstate = ws;
  float* nstate = ws + 131072;
  float* hbuf   = ws + 262144;
  float* zbuf   = ws + 524288;
  _Float16* f16a = (_Float16*)(ws + 1179648);
  _Float16* h_swz = f16a;
  _Float16* x_swz = f16a + 262144;
  _Float16* Wt2   = f16a + 262144 + 8388608;

  hipMemsetAsync(ws, 0, 262144 * sizeof(float), stream);
  pack_w<<<5120, 256, 0, stream>>>(W, Wt2);
  pack_x<<<256, 256, 0, stream>>>(x, x_swz);

  for (int d = 0; d < T + L - 1; ++d) {
    int lmin = (d > T - 1) ? d - (T - 1) : 0;
    int lmax = (d < L - 1) ? d : L - 1;
    int nc = lmax - lmin + 1;
    gemm_mfma<<<nc * NJ * 32, 512, 0, stream>>>(x_swz, h_swz, Wt2, zbuf, d, lmin);
    cell_update<<<nc * B, 256, 0, stream>>>(zbuf, bias, ln_g, ln_b,
                                            cstate, nstate, hbuf, h_swz, d, lmin);
  }
  fc_kernel<<<B, 256, 0, stream>>>(hbuf, fc_w, fc_b, out);
  finalize_copy<<<131072 / 256, 256, 0, stream>>>(hbuf, cstate, nstate, out);
}

// Round 3
// 3049.353 us; speedup vs baseline: 3.1763x; 1.5117x over previous
//
#include <hip/hip_runtime.h>
#include <hip/hip_bf16.h>
#include <math.h>

#define H 1024
#define B 32
#define T 256
#define L 4
#define O 256
#define TC 64          // time chunk
#define NCH (T / TC)   // 4

typedef _Float16 half8 __attribute__((ext_vector_type(8)));
typedef _Float16 half4 __attribute__((ext_vector_type(4)));
typedef float f32x4 __attribute__((ext_vector_type(4)));

// ws layout (offsets in halves):
//   x_pk @ 0          : 8,388,608   (T*B x H, A-frag packed)
//   hb0  @ 8388608    : 8,388,608
//   hb1  @ 16777216   : 8,388,608
//   Wt2  @ 25165824   : 20,971,520  (L*5 matrices, B-frag packed)
//   z16  @ 46137344   : 10,485,760  (one T-chunk: [TC][5][B][H] f16)
//   state f32 @ half-offset 56623104 : 262,144 f32 (c[4][32][1024], n[4][32][1024])
// total ~110 MB

#define X_PK_OFF   0
#define HB0_OFF    8388608
#define HB1_OFF    16777216
#define WT2_OFF    25165824
#define Z16_OFF    46137344
#define STATE_OFF  56623104

// ---- pack W[l][j][k][n] fp32 -> f16 B-frag layout (verified round 1)
__global__ __launch_bounds__(256) void pack_w(const float* __restrict__ W,
                                              _Float16* __restrict__ Wt2) {
  int tile = blockIdx.x;
  int m_idx = tile >> 8;            // 0..19  (= l*5+jj)
  int kt = (tile >> 4) & 15, ntt = tile & 15;
  int l = m_idx / 5, jj = m_idx % 5;
  const float* Wf = W + ((size_t)(l * 6 + jj + 1) << 20);
  _Float16* out = Wt2 + ((size_t)m_idx << 20);
  __shared__ float ts[64][65];
  int k0 = kt * 64, n0 = ntt * 64;
#pragma unroll
  for (int s = 0; s < 16; ++s) {
    int e = threadIdx.x + s * 256;
    int kk = e >> 6, col = e & 63;
    ts[kk][col] = Wf[(size_t)(k0 + kk) * H + n0 + col];
  }
  __syncthreads();
#pragma unroll
  for (int gi = 0; gi < 2; ++gi) {
    int g = threadIdx.x * 2 + gi;   // 0..511
    int l64 = g & 63, ksl = (g >> 6) & 1, ntl = g >> 7;
    int nn = l64 & 15, kh = l64 >> 4;
    half8 tmp;
#pragma unroll
    for (int e = 0; e < 8; ++e)
      tmp[e] = (_Float16)ts[ksl * 32 + kh * 8 + e][ntl * 16 + nn];
    *(half8*)&out[(size_t)((ntt * 4 + ntl) * 32 + kt * 2 + ksl) * 512 + (size_t)l64 * 8] = tmp;
  }
}

// ---- pack x fp32 -> f16 A-frag layout per t (verified round 1)
__global__ __launch_bounds__(256) void pack_x(const float* __restrict__ x,
                                              _Float16* __restrict__ x_pk) {
  int t = blockIdx.x;
  __shared__ float ld[32][257];
  for (int c = 0; c < 4; ++c) {
#pragma unroll
    for (int s = 0; s < 32; ++s) {
      int e2 = threadIdx.x + s * 256;
      int b = e2 >> 8, col = e2 & 255;
      ld[b][col] = x[((size_t)b * T + t) * H + c * 256 + col];
    }
    __syncthreads();
#pragma unroll
    for (int s3 = 0; s3 < 4; ++s3) {
      int gg = threadIdx.x * 4 + s3;  // 0..1023
      int l64 = gg & 63, ksl = (gg >> 6) & 7, bt = gg >> 9;
      int nn = l64 & 15, kh = l64 >> 4;
      int b = bt * 16 + nn;
      half8 tmp;
#pragma unroll
      for (int e = 0; e < 8; ++e)
        tmp[e] = (_Float16)ld[b][ksl * 32 + kh * 8 + e];
      *(half8*)&x_pk[(size_t)t * 32768 + (size_t)bt * 16384 +
                     (size_t)(c * 8 + ksl) * 512 + (size_t)l64 * 8] = tmp;
    }
    __syncthreads();
  }
}

// ---- big GEMM for one layer, one T-chunk:
// Z[m, n] = A[m, :] @ W[:, n],  m in [t0*32, t0*32+2048), n in [0, 5120)
// block: 512 thr = 8 waves (2m x 4n); block tile 64m x 256n; wave 32m x 64n
// grid: 32 (bm) x 20 (bn) = 640
__global__ __launch_bounds__(512) void gemm_big(
    const _Float16* __restrict__ A_pk, const _Float16* __restrict__ Wl,
    _Float16* __restrict__ z16, int t0) {
  int bi = blockIdx.x;
  int bm = bi & 31;
  int bn = bi >> 5;
  int w = threadIdx.x >> 6, lane = threadIdx.x & 63;
  int wm = w >> 2, wn = w & 3;

  const _Float16* pa = A_pk + (size_t)t0 * 32768 +
                       (size_t)(bm * 4 + wm * 2) * 16384 + (size_t)lane * 8;
  int nbase = bn * 256;
  int jj = nbase >> 10;
  int ntl0 = ((nbase & 1023) >> 4) + wn * 4;
  const _Float16* pb = Wl + ((size_t)jj << 20) + (size_t)ntl0 * 16384 + (size_t)lane * 8;

  f32x4 acc[2][4] = {};
#pragma unroll 4
  for (int ks = 0; ks < 32; ++ks) {
    half8 a0 = *(const half8*)(pa + (size_t)ks * 512);
    half8 a1 = *(const half8*)(pa + 16384 + (size_t)ks * 512);
    half8 b0 = *(const half8*)(pb + (size_t)ks * 512);
    half8 b1 = *(const half8*)(pb + 16384 + (size_t)ks * 512);
    half8 b2 = *(const half8*)(pb + 32768 + (size_t)ks * 512);
    half8 b3 = *(const half8*)(pb + 49152 + (size_t)ks * 512);
    acc[0][0] = __builtin_amdgcn_mfma_f32_16x16x32_f16(a0, b0, acc[0][0], 0, 0, 0);
    acc[0][1] = __builtin_amdgcn_mfma_f32_16x16x32_f16(a0, b1, acc[0][1], 0, 0, 0);
    acc[0][2] = __builtin_amdgcn_mfma_f32_16x16x32_f16(a0, b2, acc[0][2], 0, 0, 0);
    acc[0][3] = __builtin_amdgcn_mfma_f32_16x16x32_f16(a0, b3, acc[0][3], 0, 0, 0);
    acc[1][0] = __builtin_amdgcn_mfma_f32_16x16x32_f16(a1, b0, acc[1][0], 0, 0, 0);
    acc[1][1] = __builtin_amdgcn_mfma_f32_16x16x32_f16(a1, b1, acc[1][1], 0, 0, 0);
    acc[1][2] = __builtin_amdgcn_mfma_f32_16x16x32_f16(a1, b2, acc[1][2], 0, 0, 0);
    acc[1][3] = __builtin_amdgcn_mfma_f32_16x16x32_f16(a1, b3, acc[1][3], 0, 0, 0);
  }

  __shared__ _Float16 cz[64][264];
#pragma unroll
  for (int i = 0; i < 2; ++i)
#pragma unroll
    for (int j = 0; j < 4; ++j)
#pragma unroll
      for (int r = 0; r < 4; ++r)
        cz[(wm * 2 + i) * 16 + (lane >> 4) * 4 + r][wn * 64 + j * 16 + (lane & 15)] =
            (_Float16)acc[i][j][r];
  __syncthreads();

  int hb0 = nbase & 1023;
#pragma unroll
  for (int s = 0; s < 4; ++s) {
    int e = threadIdx.x + s * 512;
    int r = e >> 5, h8 = e & 31;
    int m_local = bm * 64 + r;
    int tc = m_local >> 5, b = m_local & 31;
    half8 vv = *(const half8*)&cz[r][h8 * 8];
    *(half8*)&z16[(((size_t)tc * 5 + jj) * 32 + b) * 1024 + hb0 + h8 * 8] = vv;
  }
}

// ---- sequential scan over one T-chunk for one layer. 32 blocks (one per b).
__global__ __launch_bounds__(256) void scan_chunk(
    const _Float16* __restrict__ z16, const _Float16* __restrict__ hin,
    const float* __restrict__ bias, const float* __restrict__ ln_g,
    const float* __restrict__ ln_b, float* __restrict__ state,
    _Float16* __restrict__ hout, float* __restrict__ out,
    int l, int t0) {
  int b = blockIdx.x;
  int tid = threadIdx.x;
  int k0 = tid * 4;

  float bz[5][4], g_[5][4], be_[5][4];
#pragma unroll
  for (int jj = 0; jj < 5; ++jj) {
    int j = jj + 1;
    float4 t1 = *(const float4*)&bias[(size_t)(l * 6 + j) * H + k0];
    float4 t2 = *(const float4*)&ln_g[(size_t)(l * 6 + j) * H + k0];
    float4 t3 = *(const float4*)&ln_b[(size_t)(l * 6 + j) * H + k0];
    bz[jj][0] = t1.x; bz[jj][1] = t1.y; bz[jj][2] = t1.z; bz[jj][3] = t1.w;
    g_[jj][0] = t2.x; g_[jj][1] = t2.y; g_[jj][2] = t2.z; g_[jj][3] = t2.w;
    be_[jj][0] = t3.x; be_[jj][1] = t3.y; be_[jj][2] = t3.z; be_[jj][3] = t3.w;
  }

  float* crow = state + ((size_t)(l * B) + b) * H + k0;
  float* nrow = state + ((size_t)((L + l) * B) + b) * H + k0;
  float c_[4] = {0.f, 0.f, 0.f, 0.f}, n_[4] = {0.f, 0.f, 0.f, 0.f};
  if (t0 > 0) {
    float4 cc = *(const float4*)crow;
    float4 nn = *(const float4*)nrow;
    c_[0] = cc.x; c_[1] = cc.y; c_[2] = cc.z; c_[3] = cc.w;
    n_[0] = nn.x; n_[1] = nn.y; n_[2] = nn.z; n_[3] = nn.w;
  }

  __shared__ float sbA[4][10];
  __shared__ float sbB[4][2];

  // frag-packed (t, b, k0) offset for hin/hout
  size_t hfoff = (size_t)(b >> 4) * 16384 + (size_t)(k0 >> 5) * 512 +
                 (size_t)((((k0 & 31) >> 3) * 16) + (b & 15)) * 8 + (k0 & 7);

  half4 zr[5];
#pragma unroll
  for (int jj = 0; jj < 5; ++jj)
    zr[jj] = *(const half4*)&z16[(((size_t)0 * 5 + jj) * 32 + b) * 1024 + k0];

  for (int tc = 0; tc < TC; ++tc) {
    int t = t0 + tc;
    half4 zc[5];
#pragma unroll
    for (int jj = 0; jj < 5; ++jj) zc[jj] = zr[jj];
    if (tc + 1 < TC) {
#pragma unroll
      for (int jj = 0; jj < 5; ++jj)
        zr[jj] = *(const half4*)&z16[(((size_t)(tc + 1) * 5 + jj) * 32 + b) * 1024 + k0];
    }
    half4 rraw;
    if (l > 0) rraw = *(const half4*)&hin[(size_t)t * 32768 + hfoff];

    float v[5][4];
    float red[10];
#pragma unroll
    for (int jj = 0; jj < 5; ++jj) {
      float s = 0.f, sq = 0.f;
#pragma unroll
      for (int u = 0; u < 4; ++u) {
        float val = (float)zc[jj][u] + bz[jj][u];
        v[jj][u] = val;
        s += val;
        sq += val * val;
      }
      red[jj * 2] = s;
      red[jj * 2 + 1] = sq;
    }
#pragma unroll
    for (int off = 32; off; off >>= 1)
#pragma unroll
      for (int q = 0; q < 10; ++q) red[q] += __shfl_down(red[q], off);
    if ((tid & 63) == 0) {
      int wv = tid >> 6;
#pragma unroll
      for (int q = 0; q < 10; ++q) sbA[wv][q] = red[q];
    }
    __syncthreads();
    float st[10];
#pragma unroll
    for (int q = 0; q < 10; ++q)
      st[q] = sbA[0][q] + sbA[1][q] + sbA[2][q] + sbA[3][q];

    float vals[5][4];
#pragma unroll
    for (int jj = 0; jj < 5; ++jj) {
      float mu = st[jj * 2] * (1.0f / H);
      float var = st[jj * 2 + 1] * (1.0f / H) - mu * mu;
      float rs = rsqrtf(var + 1e-5f);
#pragma unroll
      for (int u = 0; u < 4; ++u)
        vals[jj][u] = (v[jj][u] - mu) * rs * g_[jj][u] + be_[jj][u];
    }
    // vals: 0=k, 1=v, 2=zi, 3=zf, 4=zo
    float iv[4], fv[4], ov[4], nn2[4];
    float ksl = 0.f, nsl = 0.f;
#pragma unroll
    for (int u = 0; u < 4; ++u) {
      iv[u] = __expf(vals[2][u]);
      fv[u] = 1.f / (1.f + __expf(-vals[3][u]));
      ov[u] = 1.f / (1.f + __expf(-vals[4][u]));
      ksl += vals[0][u];
      nn2[u] = fv[u] * n_[u] + iv[u] * vals[0][u];
      nsl += nn2[u] * nn2[u];
    }
    float r2[2] = {ksl, nsl};
#pragma unroll
    for (int off = 32; off; off >>= 1) {
      r2[0] += __shfl_down(r2[0], off);
      r2[1] += __shfl_down(r2[1], off);
    }
    if ((tid & 63) == 0) {
      int wv = tid >> 6;
      sbB[wv][0] = r2[0];
      sbB[wv][1] = r2[1];
    }
    __syncthreads();
    float ksum = sbB[0][0] + sbB[1][0] + sbB[2][0] + sbB[3][0];
    float nrm = sbB[0][1] + sbB[1][1] + sbB[2][1] + sbB[3][1];
    float rn = 1.f / (sqrtf(nrm) + 1e-8f);

    float hh[4];
#pragma unroll
    for (int u = 0; u < 4; ++u) {
      float cn = fv[u] * c_[u] + iv[u] * (ksum * vals[1][u]);
      c_[u] = cn;
      n_[u] = nn2[u];
      float targ = cn * (nn2[u] * rn);
      float e2 = __expf(-2.f * fabsf(targ));
      float th = copysignf((1.f - e2) / (1.f + e2), targ);
      float resid = (l > 0) ? (float)rraw[u] : 0.f;
      hh[u] = ov[u] * th + resid;
    }

    half4 hx;
    hx[0] = (_Float16)hh[0]; hx[1] = (_Float16)hh[1];
    hx[2] = (_Float16)hh[2]; hx[3] = (_Float16)hh[3];
    *(half4*)&hout[(size_t)t * 32768 + hfoff] = hx;

    if (t == T - 1) {
      *(float4*)&out[8192 + (size_t)l * 32768 + (size_t)b * 1024 + k0] =
          make_float4(hh[0], hh[1], hh[2], hh[3]);
      *(float4*)&out[8192 + 131072 + ((size_t)(l * B) + b) * 1024 + k0] =
          make_float4(c_[0], c_[1], c_[2], c_[3]);
      *(float4*)&out[8192 + 262144 + ((size_t)(l * B) + b) * 1024 + k0] =
          make_float4(n_[0], n_[1], n_[2], n_[3]);
    }
  }

  *(float4*)crow = make_float4(c_[0], c_[1], c_[2], c_[3]);
  *(float4*)nrow = make_float4(n_[0], n_[1], n_[2], n_[3]);
}

__global__ __launch_bounds__(256) void fc_kernel(
    const float* __restrict__ out_h, const float* __restrict__ fc_w,
    const float* __restrict__ fc_b, float* __restrict__ out) {
  int b = blockIdx.x;
  int o = threadIdx.x;
  const float* hr = out_h + (size_t)b * 1024;
  float acc = fc_b[o];
#pragma unroll 4
  for (int h = 0; h < H; ++h)
    acc = fmaf(hr[h], fc_w[(size_t)h * O + o], acc);
  out[(size_t)b * O + o] = acc;
}

extern "C" void kernel_launch(void* const* d_in, const int* in_sizes, int n_in,
                              void* d_out, int out_size, void* d_ws, size_t ws_size,
                              hipStream_t stream) {
  const float* x    = (const float*)d_in[0];
  const float* W    = (const float*)d_in[1];
  const float* bias = (const float*)d_in[2];
  const float* ln_g = (const float*)d_in[3];
  const float* ln_b = (const float*)d_in[4];
  const float* fc_w = (const float*)d_in[5];
  const float* fc_b = (const float*)d_in[6];
  float* out = (float*)d_out;
  _Float16* wsh = (_Float16*)d_ws;

  _Float16* x_pk = wsh + X_PK_OFF;
  _Float16* hb[2] = {wsh + HB0_OFF, wsh + HB1_OFF};
  _Float16* Wt2  = wsh + WT2_OFF;
  _Float16* z16  = wsh + Z16_OFF;
  float* state   = (float*)(wsh + STATE_OFF);

  pack_w<<<5120, 256, 0, stream>>>(W, Wt2);
  pack_x<<<256, 256, 0, stream>>>(x, x_pk);

  for (int l = 0; l < L; ++l) {
    const _Float16* A_in = (l == 0) ? x_pk : hb[(l - 1) & 1];
    _Float16* h_out = hb[l & 1];
    const _Float16* Wl = Wt2 + ((size_t)(l * 5) << 20);
    for (int c = 0; c < NCH; ++c) {
      int t0 = c * TC;
      gemm_big<<<640, 512, 0, stream>>>(A_in, Wl, z16, t0);
      scan_chunk<<<B, 256, 0, stream>>>(z16, A_in, bias, ln_g, ln_b,
                                        state, h_out, out, l, t0);
    }
  }
  fc_kernel<<<B, 256, 0, stream>>>(out + 8192 + 3 * 32768, fc_w, fc_b, out);
}

// Round 4
// 1533.013 us; speedup vs baseline: 6.3180x; 1.9891x over previous
//
#include <hip/hip_runtime.h>
#include <hip/hip_bf16.h>
#include <math.h>

#define H 1024
#define B 32
#define T 256
#define L 4
#define O 256
#define TCH 128        // time chunk
#define NCHUNK 2

typedef _Float16 half8 __attribute__((ext_vector_type(8)));
typedef _Float16 half4 __attribute__((ext_vector_type(4)));
typedef float f32x4 __attribute__((ext_vector_type(4)));

// ws layout (offsets in halves):
#define X_PK_OFF   0            // 8,388,608  (T*32 rows, A-frag packed f16)
#define HB0_OFF    8388608      // 8,388,608
#define HB1_OFF    16777216     // 8,388,608
#define WT2_OFF    25165824     // 20,971,520 (L*5 matrices, B-frag packed f16)
#define Z16_OFF    46137344     // 20,971,520 (chunk: 4096 rows x 5 j x 1024 f16)
#define C32_OFF    67108864     // 8,388,608 halves = 4096x1024 f32
#define N32_OFF    75497472     // 8,388,608 halves
#define STATS_OFF  83886080     // 98,304 halves = 4096x12 f32
#define STATE_OFF  83984384     // 524,288 halves = 2*L*B*H f32
// total ~169 MB

// ---- pack W[l][j][k][n] fp32 -> f16 B-frag layout (verified r1/r2)
__global__ __launch_bounds__(256) void pack_w(const float* __restrict__ W,
                                              _Float16* __restrict__ Wt2) {
  int tile = blockIdx.x;
  int m_idx = tile >> 8;            // 0..19  (= l*5+jj)
  int kt = (tile >> 4) & 15, ntt = tile & 15;
  int l = m_idx / 5, jj = m_idx % 5;
  const float* Wf = W + ((size_t)(l * 6 + jj + 1) << 20);
  _Float16* out = Wt2 + ((size_t)m_idx << 20);
  __shared__ float ts[64][65];
  int k0 = kt * 64, n0 = ntt * 64;
#pragma unroll
  for (int s = 0; s < 16; ++s) {
    int e = threadIdx.x + s * 256;
    int kk = e >> 6, col = e & 63;
    ts[kk][col] = Wf[(size_t)(k0 + kk) * H + n0 + col];
  }
  __syncthreads();
#pragma unroll
  for (int gi = 0; gi < 2; ++gi) {
    int g = threadIdx.x * 2 + gi;   // 0..511
    int l64 = g & 63, ksl = (g >> 6) & 1, ntl = g >> 7;
    int nn = l64 & 15, kh = l64 >> 4;
    half8 tmp;
#pragma unroll
    for (int e = 0; e < 8; ++e)
      tmp[e] = (_Float16)ts[ksl * 32 + kh * 8 + e][ntl * 16 + nn];
    *(half8*)&out[(size_t)((ntt * 4 + ntl) * 32 + kt * 2 + ksl) * 512 + (size_t)l64 * 8] = tmp;
  }
}

// ---- pack x fp32 -> f16 A-frag layout per t (verified r1/r2)
__global__ __launch_bounds__(256) void pack_x(const float* __restrict__ x,
                                              _Float16* __restrict__ x_pk) {
  int t = blockIdx.x;
  __shared__ float ld[32][257];
  for (int c = 0; c < 4; ++c) {
#pragma unroll
    for (int s = 0; s < 32; ++s) {
      int e2 = threadIdx.x + s * 256;
      int b = e2 >> 8, col = e2 & 255;
      ld[b][col] = x[((size_t)b * T + t) * H + c * 256 + col];
    }
    __syncthreads();
#pragma unroll
    for (int s3 = 0; s3 < 4; ++s3) {
      int gg = threadIdx.x * 4 + s3;  // 0..1023
      int l64 = gg & 63, ksl = (gg >> 6) & 7, bt = gg >> 9;
      int nn = l64 & 15, kh = l64 >> 4;
      int b = bt * 16 + nn;
      half8 tmp;
#pragma unroll
      for (int e = 0; e < 8; ++e)
        tmp[e] = (_Float16)ld[b][ksl * 32 + kh * 8 + e];
      *(half8*)&x_pk[(size_t)t * 32768 + (size_t)bt * 16384 +
                     (size_t)(c * 8 + ksl) * 512 + (size_t)l64 * 8] = tmp;
    }
    __syncthreads();
  }
}

// ---- GEMM one layer, one T-chunk (4096 rows): Z = A @ W, N=5120
// block 512 thr = 8 waves (2wm x 4wn), wave tile 64m x 64n -> block 128m x 256n
// grid 640: bm 0..31, bn 0..19; XCD-chunked swizzle (bn-major chunks)
__global__ __launch_bounds__(512) void gemm_big(
    const _Float16* __restrict__ A_pk, const _Float16* __restrict__ Wl,
    _Float16* __restrict__ z16, int t0) {
  int raw = blockIdx.x;
  int swz = (raw & 7) * 80 + (raw >> 3);   // 640 = 8 XCD x 80, bijective
  int bm = swz & 31;
  int bn = swz >> 5;
  int w = threadIdx.x >> 6, lane = threadIdx.x & 63;
  int wm = w >> 2, wn = w & 3;

  const _Float16* pa = A_pk + ((size_t)(t0 * 2 + bm * 8 + wm * 4)) * 16384 + lane * 8;
  int j = bn >> 2;
  int nt16_0 = (bn & 3) * 16 + wn * 4;
  const _Float16* pb = Wl + ((size_t)j << 20) + (size_t)nt16_0 * 16384 + lane * 8;

  f32x4 acc[4][4] = {};
#pragma unroll 2
  for (int ks = 0; ks < 32; ++ks) {
    half8 a[4], b[4];
#pragma unroll
    for (int i = 0; i < 4; ++i) a[i] = *(const half8*)(pa + (size_t)i * 16384 + ks * 512);
#pragma unroll
    for (int i = 0; i < 4; ++i) b[i] = *(const half8*)(pb + (size_t)i * 16384 + ks * 512);
#pragma unroll
    for (int i = 0; i < 4; ++i)
#pragma unroll
      for (int jf = 0; jf < 4; ++jf)
        acc[i][jf] = __builtin_amdgcn_mfma_f32_16x16x32_f16(a[i], b[jf], acc[i][jf], 0, 0, 0);
  }

  __shared__ _Float16 cz[64][264];
  int hb0 = (bn & 3) * 256;
  for (int p = 0; p < 2; ++p) {
    if (p) __syncthreads();
    if (wm == p) {
#pragma unroll
      for (int i = 0; i < 4; ++i)
#pragma unroll
        for (int jf = 0; jf < 4; ++jf)
#pragma unroll
          for (int r = 0; r < 4; ++r)
            cz[i * 16 + (lane >> 4) * 4 + r][wn * 64 + jf * 16 + (lane & 15)] =
                (_Float16)acc[i][jf][r];
    }
    __syncthreads();
#pragma unroll
    for (int s = 0; s < 4; ++s) {
      int e = threadIdx.x + s * 512;
      int r = e >> 5, h8 = e & 31;
      int m_local = bm * 128 + p * 64 + r;
      half8 vv = *(const half8*)&cz[r][h8 * 8];
      *(half8*)&z16[((size_t)m_local * 5 + j) * 1024 + hb0 + h8 * 8] = vv;
    }
  }
}

// ---- per-row LN stats + ksum. block per row (4096 rows/chunk).
// stats row: [mu0,rs0, mu1,rs1, mu2,rs2, mu3,rs3, mu4,rs4, ksum, pad]
__global__ __launch_bounds__(256) void stats_kernel(
    const _Float16* __restrict__ z16, const float* __restrict__ bias,
    const float* __restrict__ ln_g, const float* __restrict__ ln_b,
    float* __restrict__ stats, int l) {
  int row = blockIdx.x, tid = threadIdx.x;
  int h0 = tid * 4;
  float red[13];
#pragma unroll
  for (int jj = 0; jj < 5; ++jj) {
    half4 z4 = *(const half4*)&z16[((size_t)row * 5 + jj) * 1024 + h0];
    float4 bb = *(const float4*)&bias[(size_t)(l * 6 + 1 + jj) * H + h0];
    float vx = (float)z4[0] + bb.x, vy = (float)z4[1] + bb.y,
          vz = (float)z4[2] + bb.z, vw = (float)z4[3] + bb.w;
    red[jj * 2] = vx + vy + vz + vw;
    red[jj * 2 + 1] = vx * vx + vy * vy + vz * vz + vw * vw;
    if (jj == 0) {
      float4 g = *(const float4*)&ln_g[(size_t)(l * 6 + 1) * H + h0];
      float4 be = *(const float4*)&ln_b[(size_t)(l * 6 + 1) * H + h0];
      red[10] = vx * g.x + vy * g.y + vz * g.z + vw * g.w;
      red[11] = g.x + g.y + g.z + g.w;
      red[12] = be.x + be.y + be.z + be.w;
    }
  }
#pragma unroll
  for (int off = 32; off; off >>= 1)
#pragma unroll
    for (int q = 0; q < 13; ++q) red[q] += __shfl_down(red[q], off);
  __shared__ float sb[4][13];
  if ((tid & 63) == 0) {
#pragma unroll
    for (int q = 0; q < 13; ++q) sb[tid >> 6][q] = red[q];
  }
  __syncthreads();
  if (tid == 0) {
    float st[13];
#pragma unroll
    for (int q = 0; q < 13; ++q) st[q] = sb[0][q] + sb[1][q] + sb[2][q] + sb[3][q];
    float* so = stats + (size_t)row * 12;
#pragma unroll
    for (int jj = 0; jj < 5; ++jj) {
      float mu = st[jj * 2] * (1.0f / H);
      float var = st[jj * 2 + 1] * (1.0f / H) - mu * mu;
      so[jj * 2] = mu;
      so[jj * 2 + 1] = rsqrtf(var + 1e-5f);
    }
    float mu0 = st[0] * (1.0f / H);
    float rs0 = rsqrtf(st[1] * (1.0f / H) - mu0 * mu0 + 1e-5f);
    so[10] = rs0 * (st[10] - mu0 * st[11]) + st[12];
    so[11] = 0.f;
  }
}

// ---- elementwise scan over t: one thread per (b,h), 512 single-wave blocks
__global__ __launch_bounds__(64) void scan_kernel(
    const _Float16* __restrict__ z16, const float* __restrict__ stats,
    const float* __restrict__ bias, const float* __restrict__ ln_g,
    const float* __restrict__ ln_b, float* __restrict__ state,
    float* __restrict__ c32, float* __restrict__ n32, int l, int t0) {
  int b = blockIdx.x >> 4;
  int h = ((blockIdx.x & 15) << 6) + threadIdx.x;
  float bz[4], gg[4], bb[4];
#pragma unroll
  for (int jj = 0; jj < 4; ++jj) {
    bz[jj] = bias[(size_t)(l * 6 + 1 + jj) * H + h];
    gg[jj] = ln_g[(size_t)(l * 6 + 1 + jj) * H + h];
    bb[jj] = ln_b[(size_t)(l * 6 + 1 + jj) * H + h];
  }
  size_t sidx = ((size_t)l * B + b) * H + h;
  float c_ = 0.f, n_ = 0.f;
  if (t0 > 0) {
    c_ = state[sidx];
    n_ = state[(size_t)L * B * H + sidx];
  }
  for (int tc = 0; tc < TCH; ++tc) {
    int row = tc * 32 + b;
    size_t zb = ((size_t)row * 5) * 1024 + h;
    float zk = (float)z16[zb];
    float zv = (float)z16[zb + 1024];
    float zi = (float)z16[zb + 2048];
    float zf = (float)z16[zb + 3072];
    const float* st = stats + (size_t)row * 12;
    float k  = (zk + bz[0] - st[0]) * st[1] * gg[0] + bb[0];
    float v  = (zv + bz[1] - st[2]) * st[3] * gg[1] + bb[1];
    float zi_ = (zi + bz[2] - st[4]) * st[5] * gg[2] + bb[2];
    float zf_ = (zf + bz[3] - st[6]) * st[7] * gg[3] + bb[3];
    float iv = __expf(zi_);
    float fv = 1.f / (1.f + __expf(-zf_));
    n_ = fv * n_ + iv * k;
    c_ = fv * c_ + iv * (st[10] * v);
    n32[(size_t)row * 1024 + h] = n_;
    c32[(size_t)row * 1024 + h] = c_;
  }
  state[sidx] = c_;
  state[(size_t)L * B * H + sidx] = n_;
}

// ---- final: block per row; ||n|| reduce + o-gate + tanh + resid + pack
__global__ __launch_bounds__(256) void final_kernel(
    const _Float16* __restrict__ z16, const float* __restrict__ stats,
    const float* __restrict__ bias, const float* __restrict__ ln_g,
    const float* __restrict__ ln_b, const float* __restrict__ c32,
    const float* __restrict__ n32, const _Float16* __restrict__ hin,
    _Float16* __restrict__ hout, float* __restrict__ out, int l, int t0) {
  int row = blockIdx.x;
  int b = row & 31, tc = row >> 5, t = t0 + tc;
  int tid = threadIdx.x, h0 = tid * 4;
  float4 n4 = *(const float4*)&n32[(size_t)row * 1024 + h0];
  float ss = n4.x * n4.x + n4.y * n4.y + n4.z * n4.z + n4.w * n4.w;
#pragma unroll
  for (int off = 32; off; off >>= 1) ss += __shfl_down(ss, off);
  __shared__ float sb[4];
  if ((tid & 63) == 0) sb[tid >> 6] = ss;
  __syncthreads();
  float rn = 1.f / (sqrtf(sb[0] + sb[1] + sb[2] + sb[3]) + 1e-8f);

  float4 c4 = *(const float4*)&c32[(size_t)row * 1024 + h0];
  half4 zo4 = *(const half4*)&z16[((size_t)row * 5 + 4) * 1024 + h0];
  const float* st = stats + (size_t)row * 12;
  float mu = st[8], rs = st[9];
  float4 bz = *(const float4*)&bias[(size_t)(l * 6 + 5) * H + h0];
  float4 g4 = *(const float4*)&ln_g[(size_t)(l * 6 + 5) * H + h0];
  float4 be4 = *(const float4*)&ln_b[(size_t)(l * 6 + 5) * H + h0];
  float gv[4] = {g4.x, g4.y, g4.z, g4.w};
  float bev[4] = {be4.x, be4.y, be4.z, be4.w};
  float zov[4] = {(float)zo4[0] + bz.x, (float)zo4[1] + bz.y,
                  (float)zo4[2] + bz.z, (float)zo4[3] + bz.w};
  float cc[4] = {c4.x, c4.y, c4.z, c4.w};
  float nn[4] = {n4.x, n4.y, n4.z, n4.w};

  size_t hfoff = (size_t)(b >> 4) * 16384 + (size_t)(h0 >> 5) * 512 +
                 (size_t)((((h0 & 31) >> 3) * 16) + (b & 15)) * 8 + (h0 & 7);
  half4 rin;
  if (l > 0) rin = *(const half4*)&hin[(size_t)t * 32768 + hfoff];

  float hh[4];
#pragma unroll
  for (int u = 0; u < 4; ++u) {
    float ov = 1.f / (1.f + __expf(-((zov[u] - mu) * rs * gv[u] + bev[u])));
    float targ = cc[u] * (nn[u] * rn);
    float e2 = __expf(-2.f * fabsf(targ));
    float th = copysignf((1.f - e2) / (1.f + e2), targ);
    hh[u] = ov * th + ((l > 0) ? (float)rin[u] : 0.f);
  }
  half4 hx;
  hx[0] = (_Float16)hh[0]; hx[1] = (_Float16)hh[1];
  hx[2] = (_Float16)hh[2]; hx[3] = (_Float16)hh[3];
  *(half4*)&hout[(size_t)t * 32768 + hfoff] = hx;

  if (t == T - 1) {
    *(float4*)&out[8192 + (size_t)l * 32768 + (size_t)b * 1024 + h0] =
        make_float4(hh[0], hh[1], hh[2], hh[3]);
    *(float4*)&out[8192 + 131072 + ((size_t)(l * B) + b) * 1024 + h0] =
        make_float4(cc[0], cc[1], cc[2], cc[3]);
    *(float4*)&out[8192 + 262144 + ((size_t)(l * B) + b) * 1024 + h0] =
        make_float4(nn[0], nn[1], nn[2], nn[3]);
  }
}

__global__ __launch_bounds__(256) void fc_kernel(
    const float* __restrict__ out_h, const float* __restrict__ fc_w,
    const float* __restrict__ fc_b, float* __restrict__ out) {
  int b = blockIdx.x;
  int o = threadIdx.x;
  const float* hr = out_h + (size_t)b * 1024;
  float acc = fc_b[o];
#pragma unroll 4
  for (int h = 0; h < H; ++h)
    acc = fmaf(hr[h], fc_w[(size_t)h * O + o], acc);
  out[(size_t)b * O + o] = acc;
}

extern "C" void kernel_launch(void* const* d_in, const int* in_sizes, int n_in,
                              void* d_out, int out_size, void* d_ws, size_t ws_size,
                              hipStream_t stream) {
  const float* x    = (const float*)d_in[0];
  const float* W    = (const float*)d_in[1];
  const float* bias = (const float*)d_in[2];
  const float* ln_g = (const float*)d_in[3];
  const float* ln_b = (const float*)d_in[4];
  const float* fc_w = (const float*)d_in[5];
  const float* fc_b = (const float*)d_in[6];
  float* out = (float*)d_out;
  _Float16* wsh = (_Float16*)d_ws;

  _Float16* x_pk = wsh + X_PK_OFF;
  _Float16* hb[2] = {wsh + HB0_OFF, wsh + HB1_OFF};
  _Float16* Wt2  = wsh + WT2_OFF;
  _Float16* z16  = wsh + Z16_OFF;
  float* c32   = (float*)(wsh + C32_OFF);
  float* n32   = (float*)(wsh + N32_OFF);
  float* stats = (float*)(wsh + STATS_OFF);
  float* state = (float*)(wsh + STATE_OFF);

  pack_w<<<5120, 256, 0, stream>>>(W, Wt2);
  pack_x<<<256, 256, 0, stream>>>(x, x_pk);

  for (int l = 0; l < L; ++l) {
    const _Float16* A_in = (l == 0) ? x_pk : hb[(l - 1) & 1];
    _Float16* h_out = hb[l & 1];
    const _Float16* Wl = Wt2 + ((size_t)(l * 5) << 20);
    for (int c = 0; c < NCHUNK; ++c) {
      int t0 = c * TCH;
      gemm_big<<<640, 512, 0, stream>>>(A_in, Wl, z16, t0);
      stats_kernel<<<4096, 256, 0, stream>>>(z16, bias, ln_g, ln_b, stats, l);
      scan_kernel<<<512, 64, 0, stream>>>(z16, stats, bias, ln_g, ln_b,
                                          state, c32, n32, l, t0);
      final_kernel<<<4096, 256, 0, stream>>>(z16, stats, bias, ln_g, ln_b,
                                             c32, n32, A_in, h_out, out, l, t0);
    }
  }
  fc_kernel<<<B, 256, 0, stream>>>(out + 8192 + 3 * 32768, fc_w, fc_b, out);
}

// Round 5
// 1160.782 us; speedup vs baseline: 8.3441x; 1.3207x over previous
//
#include <hip/hip_runtime.h>
#include <hip/hip_bf16.h>
#include <math.h>

#define H 1024
#define B 32
#define T 256
#define L 4
#define O 256
#define TCH 128        // time chunk
#define NCHUNK 2
#define SEGLEN 16
#define NSEG (TCH / SEGLEN)   // 8

typedef _Float16 half8 __attribute__((ext_vector_type(8)));
typedef _Float16 half4 __attribute__((ext_vector_type(4)));
typedef float f32x4 __attribute__((ext_vector_type(4)));

// ws layout (offsets in halves):
#define X_PK_OFF   0            // 8,388,608 halves (T*32 rows, A-frag f16)
#define HB0_OFF    8388608
#define HB1_OFF    16777216
#define WT2_OFF    25165824     // 20,971,520 halves
#define Z16_OFF    46137344     // 20,971,520 halves (chunk: 4096 rows x 5 x 1024 f16)
#define A_OFF      67108864     // 8,388,608 halves = 4096x1024 f32 (prefix prod of f)
#define BC_OFF     75497472     // 8,388,608 halves (local c-scan)
#define BN_OFF     83886080     // 8,388,608 halves (local n-scan)
#define STATS_OFF  92274688     // 98,304 halves = 4096x12 f32
#define CARC_OFF   92372992     // 524,288 halves = 8x32768 f32
#define CARN_OFF   92897280     // 524,288 halves
#define STATE_OFF  93421568     // 524,288 halves = 2*L*B*H f32
#define FCP_OFF    93945856     // 131,072 halves = 65536 f32
// total ~188 MB

// ---- pack W[l][j][k][n] fp32 -> f16 B-frag layout (verified r1-r3)
__global__ __launch_bounds__(256) void pack_w(const float* __restrict__ W,
                                              _Float16* __restrict__ Wt2) {
  int tile = blockIdx.x;
  int m_idx = tile >> 8;            // 0..19  (= l*5+jj)
  int kt = (tile >> 4) & 15, ntt = tile & 15;
  int l = m_idx / 5, jj = m_idx % 5;
  const float* Wf = W + ((size_t)(l * 6 + jj + 1) << 20);
  _Float16* out = Wt2 + ((size_t)m_idx << 20);
  __shared__ float ts[64][65];
  int k0 = kt * 64, n0 = ntt * 64;
#pragma unroll
  for (int s = 0; s < 16; ++s) {
    int e = threadIdx.x + s * 256;
    int kk = e >> 6, col = e & 63;
    ts[kk][col] = Wf[(size_t)(k0 + kk) * H + n0 + col];
  }
  __syncthreads();
#pragma unroll
  for (int gi = 0; gi < 2; ++gi) {
    int g = threadIdx.x * 2 + gi;   // 0..511
    int l64 = g & 63, ksl = (g >> 6) & 1, ntl = g >> 7;
    int nn = l64 & 15, kh = l64 >> 4;
    half8 tmp;
#pragma unroll
    for (int e = 0; e < 8; ++e)
      tmp[e] = (_Float16)ts[ksl * 32 + kh * 8 + e][ntl * 16 + nn];
    *(half8*)&out[(size_t)((ntt * 4 + ntl) * 32 + kt * 2 + ksl) * 512 + (size_t)l64 * 8] = tmp;
  }
}

// ---- pack x fp32 -> f16 A-frag layout per t (verified r1-r3)
__global__ __launch_bounds__(256) void pack_x(const float* __restrict__ x,
                                              _Float16* __restrict__ x_pk) {
  int t = blockIdx.x;
  __shared__ float ld[32][257];
  for (int c = 0; c < 4; ++c) {
#pragma unroll
    for (int s = 0; s < 32; ++s) {
      int e2 = threadIdx.x + s * 256;
      int b = e2 >> 8, col = e2 & 255;
      ld[b][col] = x[((size_t)b * T + t) * H + c * 256 + col];
    }
    __syncthreads();
#pragma unroll
    for (int s3 = 0; s3 < 4; ++s3) {
      int gg = threadIdx.x * 4 + s3;  // 0..1023
      int l64 = gg & 63, ksl = (gg >> 6) & 7, bt = gg >> 9;
      int nn = l64 & 15, kh = l64 >> 4;
      int b = bt * 16 + nn;
      half8 tmp;
#pragma unroll
      for (int e = 0; e < 8; ++e)
        tmp[e] = (_Float16)ld[b][ksl * 32 + kh * 8 + e];
      *(half8*)&x_pk[(size_t)t * 32768 + (size_t)bt * 16384 +
                     (size_t)(c * 8 + ksl) * 512 + (size_t)l64 * 8] = tmp;
    }
    __syncthreads();
  }
}

// ---- GEMM (verified r3): block 128m x 256n, 8 waves, grid 640, XCD swizzle
__global__ __launch_bounds__(512) void gemm_big(
    const _Float16* __restrict__ A_pk, const _Float16* __restrict__ Wl,
    _Float16* __restrict__ z16, int t0) {
  int raw = blockIdx.x;
  int swz = (raw & 7) * 80 + (raw >> 3);   // 640 = 8 XCD x 80, bijective
  int bm = swz & 31;
  int bn = swz >> 5;
  int w = threadIdx.x >> 6, lane = threadIdx.x & 63;
  int wm = w >> 2, wn = w & 3;

  const _Float16* pa = A_pk + ((size_t)(t0 * 2 + bm * 8 + wm * 4)) * 16384 + lane * 8;
  int j = bn >> 2;
  int nt16_0 = (bn & 3) * 16 + wn * 4;
  const _Float16* pb = Wl + ((size_t)j << 20) + (size_t)nt16_0 * 16384 + lane * 8;

  f32x4 acc[4][4] = {};
#pragma unroll 2
  for (int ks = 0; ks < 32; ++ks) {
    half8 a[4], b[4];
#pragma unroll
    for (int i = 0; i < 4; ++i) a[i] = *(const half8*)(pa + (size_t)i * 16384 + ks * 512);
#pragma unroll
    for (int i = 0; i < 4; ++i) b[i] = *(const half8*)(pb + (size_t)i * 16384 + ks * 512);
#pragma unroll
    for (int i = 0; i < 4; ++i)
#pragma unroll
      for (int jf = 0; jf < 4; ++jf)
        acc[i][jf] = __builtin_amdgcn_mfma_f32_16x16x32_f16(a[i], b[jf], acc[i][jf], 0, 0, 0);
  }

  __shared__ _Float16 cz[64][264];
  int hb0 = (bn & 3) * 256;
  for (int p = 0; p < 2; ++p) {
    if (p) __syncthreads();
    if (wm == p) {
#pragma unroll
      for (int i = 0; i < 4; ++i)
#pragma unroll
        for (int jf = 0; jf < 4; ++jf)
#pragma unroll
          for (int r = 0; r < 4; ++r)
            cz[i * 16 + (lane >> 4) * 4 + r][wn * 64 + jf * 16 + (lane & 15)] =
                (_Float16)acc[i][jf][r];
    }
    __syncthreads();
#pragma unroll
    for (int s = 0; s < 4; ++s) {
      int e = threadIdx.x + s * 512;
      int r = e >> 5, h8 = e & 31;
      int m_local = bm * 128 + p * 64 + r;
      half8 vv = *(const half8*)&cz[r][h8 * 8];
      *(half8*)&z16[((size_t)m_local * 5 + j) * 1024 + hb0 + h8 * 8] = vv;
    }
  }
}

// ---- per-row LN stats + ksum (verified r3)
__global__ __launch_bounds__(256) void stats_kernel(
    const _Float16* __restrict__ z16, const float* __restrict__ bias,
    const float* __restrict__ ln_g, const float* __restrict__ ln_b,
    float* __restrict__ stats, int l) {
  int row = blockIdx.x, tid = threadIdx.x;
  int h0 = tid * 4;
  float red[13];
#pragma unroll
  for (int jj = 0; jj < 5; ++jj) {
    half4 z4 = *(const half4*)&z16[((size_t)row * 5 + jj) * 1024 + h0];
    float4 bb = *(const float4*)&bias[(size_t)(l * 6 + 1 + jj) * H + h0];
    float vx = (float)z4[0] + bb.x, vy = (float)z4[1] + bb.y,
          vz = (float)z4[2] + bb.z, vw = (float)z4[3] + bb.w;
    red[jj * 2] = vx + vy + vz + vw;
    red[jj * 2 + 1] = vx * vx + vy * vy + vz * vz + vw * vw;
    if (jj == 0) {
      float4 g = *(const float4*)&ln_g[(size_t)(l * 6 + 1) * H + h0];
      float4 be = *(const float4*)&ln_b[(size_t)(l * 6 + 1) * H + h0];
      red[10] = vx * g.x + vy * g.y + vz * g.z + vw * g.w;
      red[11] = g.x + g.y + g.z + g.w;
      red[12] = be.x + be.y + be.z + be.w;
    }
  }
#pragma unroll
  for (int off = 32; off; off >>= 1)
#pragma unroll
    for (int q = 0; q < 13; ++q) red[q] += __shfl_down(red[q], off);
  __shared__ float sb[4][13];
  if ((tid & 63) == 0) {
#pragma unroll
    for (int q = 0; q < 13; ++q) sb[tid >> 6][q] = red[q];
  }
  __syncthreads();
  if (tid == 0) {
    float st[13];
#pragma unroll
    for (int q = 0; q < 13; ++q) st[q] = sb[0][q] + sb[1][q] + sb[2][q] + sb[3][q];
    float* so = stats + (size_t)row * 12;
#pragma unroll
    for (int jj = 0; jj < 5; ++jj) {
      float mu = st[jj * 2] * (1.0f / H);
      float var = st[jj * 2 + 1] * (1.0f / H) - mu * mu;
      so[jj * 2] = mu;
      so[jj * 2 + 1] = rsqrtf(var + 1e-5f);
    }
    float mu0 = st[0] * (1.0f / H);
    float rs0 = rsqrtf(st[1] * (1.0f / H) - mu0 * mu0 + 1e-5f);
    so[10] = rs0 * (st[10] - mu0 * st[11]) + st[12];
    so[11] = 0.f;
  }
}

// ---- scan pass 1: per-segment local scans. thread = (seg, b, h).
// A_t = prod f (inclusive), Bn_t/Bc_t = local recurrence with zero init.
__global__ __launch_bounds__(256) void scan_p1(
    const _Float16* __restrict__ z16, const float* __restrict__ stats,
    const float* __restrict__ bias, const float* __restrict__ ln_g,
    const float* __restrict__ ln_b, float* __restrict__ Abuf,
    float* __restrict__ Bc, float* __restrict__ Bn, int l) {
  int idx = blockIdx.x * 256 + threadIdx.x;   // 262144 threads
  int h = idx & 1023;
  int bs = idx >> 10;
  int b = bs & 31, seg = bs >> 5;

  float bz[4], gg[4], bb[4];
#pragma unroll
  for (int jj = 0; jj < 4; ++jj) {
    bz[jj] = bias[(size_t)(l * 6 + 1 + jj) * H + h];
    gg[jj] = ln_g[(size_t)(l * 6 + 1 + jj) * H + h];
    bb[jj] = ln_b[(size_t)(l * 6 + 1 + jj) * H + h];
  }
  float A = 1.f, bc = 0.f, bn = 0.f;
#pragma unroll 2
  for (int u = 0; u < SEGLEN; ++u) {
    int row = (seg * SEGLEN + u) * 32 + b;
    size_t zb = ((size_t)row * 5) * 1024 + h;
    float zk = (float)z16[zb];
    float zv = (float)z16[zb + 1024];
    float zi = (float)z16[zb + 2048];
    float zf = (float)z16[zb + 3072];
    const float* st = stats + (size_t)row * 12;
    float k   = (zk + bz[0] - st[0]) * st[1] * gg[0] + bb[0];
    float v   = (zv + bz[1] - st[2]) * st[3] * gg[1] + bb[1];
    float zi_ = (zi + bz[2] - st[4]) * st[5] * gg[2] + bb[2];
    float zf_ = (zf + bz[3] - st[6]) * st[7] * gg[3] + bb[3];
    float iv = __expf(zi_);
    float fv = 1.f / (1.f + __expf(-zf_));
    A *= fv;
    bn = fv * bn + iv * k;
    bc = fv * bc + iv * (st[10] * v);
    size_t o = (size_t)row * 1024 + h;
    Abuf[o] = A;
    Bn[o] = bn;
    Bc[o] = bc;
  }
}

// ---- scan pass 2: carry-in per segment, per (b,h). 32768 threads.
__global__ __launch_bounds__(256) void scan_p2(
    const float* __restrict__ Abuf, const float* __restrict__ Bc,
    const float* __restrict__ Bn, float* __restrict__ state,
    float* __restrict__ carC, float* __restrict__ carN, int l, int t0) {
  int idx = blockIdx.x * 256 + threadIdx.x;   // 32768
  int h = idx & 1023, b = idx >> 10;
  size_t sidx = ((size_t)l * B + b) * H + h;
  float cc = 0.f, nn = 0.f;
  if (t0 > 0) {
    cc = state[sidx];
    nn = state[(size_t)L * B * H + sidx];
  }
#pragma unroll
  for (int seg = 0; seg < NSEG; ++seg) {
    size_t coff = (size_t)seg * 32768 + (size_t)b * 1024 + h;
    carC[coff] = cc;
    carN[coff] = nn;
    int rowLast = (seg * SEGLEN + SEGLEN - 1) * 32 + b;
    size_t o = (size_t)rowLast * 1024 + h;
    float a = Abuf[o];
    cc = Bc[o] + a * cc;
    nn = Bn[o] + a * nn;
  }
  state[sidx] = cc;
  state[(size_t)L * B * H + sidx] = nn;
}

// ---- final: c,n = B + A*carry; ||n|| reduce + o-gate + tanh + resid + pack
__global__ __launch_bounds__(256) void final_kernel(
    const _Float16* __restrict__ z16, const float* __restrict__ stats,
    const float* __restrict__ bias, const float* __restrict__ ln_g,
    const float* __restrict__ ln_b, const float* __restrict__ Abuf,
    const float* __restrict__ Bc, const float* __restrict__ Bn,
    const float* __restrict__ carC, const float* __restrict__ carN,
    const _Float16* __restrict__ hin, _Float16* __restrict__ hout,
    float* __restrict__ out, int l, int t0) {
  int row = blockIdx.x;
  int b = row & 31, tc = row >> 5, t = t0 + tc, seg = tc / SEGLEN;
  int tid = threadIdx.x, h0 = tid * 4;
  size_t o = (size_t)row * 1024 + h0;
  size_t coff = (size_t)seg * 32768 + (size_t)b * 1024 + h0;
  float4 a4 = *(const float4*)&Abuf[o];
  float4 bn4 = *(const float4*)&Bn[o];
  float4 bc4 = *(const float4*)&Bc[o];
  float4 cN = *(const float4*)&carN[coff];
  float4 cC = *(const float4*)&carC[coff];
  float nn[4] = {bn4.x + a4.x * cN.x, bn4.y + a4.y * cN.y,
                 bn4.z + a4.z * cN.z, bn4.w + a4.w * cN.w};
  float cc[4] = {bc4.x + a4.x * cC.x, bc4.y + a4.y * cC.y,
                 bc4.z + a4.z * cC.z, bc4.w + a4.w * cC.w};

  float ss = nn[0] * nn[0] + nn[1] * nn[1] + nn[2] * nn[2] + nn[3] * nn[3];
#pragma unroll
  for (int off = 32; off; off >>= 1) ss += __shfl_down(ss, off);
  __shared__ float sb[4];
  if ((tid & 63) == 0) sb[tid >> 6] = ss;
  __syncthreads();
  float rn = 1.f / (sqrtf(sb[0] + sb[1] + sb[2] + sb[3]) + 1e-8f);

  half4 zo4 = *(const half4*)&z16[((size_t)row * 5 + 4) * 1024 + h0];
  const float* st = stats + (size_t)row * 12;
  float mu = st[8], rs = st[9];
  float4 bz = *(const float4*)&bias[(size_t)(l * 6 + 5) * H + h0];
  float4 g4 = *(const float4*)&ln_g[(size_t)(l * 6 + 5) * H + h0];
  float4 be4 = *(const float4*)&ln_b[(size_t)(l * 6 + 5) * H + h0];
  float gv[4] = {g4.x, g4.y, g4.z, g4.w};
  float bev[4] = {be4.x, be4.y, be4.z, be4.w};
  float zov[4] = {(float)zo4[0] + bz.x, (float)zo4[1] + bz.y,
                  (float)zo4[2] + bz.z, (float)zo4[3] + bz.w};

  size_t hfoff = (size_t)(b >> 4) * 16384 + (size_t)(h0 >> 5) * 512 +
                 (size_t)((((h0 & 31) >> 3) * 16) + (b & 15)) * 8 + (h0 & 7);
  half4 rin;
  if (l > 0) rin = *(const half4*)&hin[(size_t)t * 32768 + hfoff];

  float hh[4];
#pragma unroll
  for (int u = 0; u < 4; ++u) {
    float ov = 1.f / (1.f + __expf(-((zov[u] - mu) * rs * gv[u] + bev[u])));
    float targ = cc[u] * (nn[u] * rn);
    float e2 = __expf(-2.f * fabsf(targ));
    float th = copysignf((1.f - e2) / (1.f + e2), targ);
    hh[u] = ov * th + ((l > 0) ? (float)rin[u] : 0.f);
  }
  half4 hx;
  hx[0] = (_Float16)hh[0]; hx[1] = (_Float16)hh[1];
  hx[2] = (_Float16)hh[2]; hx[3] = (_Float16)hh[3];
  *(half4*)&hout[(size_t)t * 32768 + hfoff] = hx;

  if (t == T - 1) {
    *(float4*)&out[8192 + (size_t)l * 32768 + (size_t)b * 1024 + h0] =
        make_float4(hh[0], hh[1], hh[2], hh[3]);
    *(float4*)&out[8192 + 131072 + ((size_t)(l * B) + b) * 1024 + h0] =
        make_float4(cc[0], cc[1], cc[2], cc[3]);
    *(float4*)&out[8192 + 262144 + ((size_t)(l * B) + b) * 1024 + h0] =
        make_float4(nn[0], nn[1], nn[2], nn[3]);
  }
}

// ---- fc: split-K partials (256 blocks) + reduce (32 blocks)
__global__ __launch_bounds__(256) void fc_part(
    const float* __restrict__ out_h, const float* __restrict__ fc_w,
    float* __restrict__ partial) {
  int b = blockIdx.x >> 3, kh = blockIdx.x & 7;
  int o = threadIdx.x;
  const float* hr = out_h + (size_t)b * 1024 + kh * 128;
  const float* wp = fc_w + (size_t)kh * 128 * O + o;
  float acc = 0.f;
#pragma unroll 8
  for (int h = 0; h < 128; ++h)
    acc = fmaf(hr[h], wp[(size_t)h * O], acc);
  partial[((size_t)kh * 32 + b) * O + o] = acc;
}

__global__ __launch_bounds__(256) void fc_reduce(
    const float* __restrict__ partial, const float* __restrict__ fc_b,
    float* __restrict__ out) {
  int b = blockIdx.x, o = threadIdx.x;
  float acc = fc_b[o];
#pragma unroll
  for (int kh = 0; kh < 8; ++kh)
    acc += partial[((size_t)kh * 32 + b) * O + o];
  out[(size_t)b * O + o] = acc;
}

extern "C" void kernel_launch(void* const* d_in, const int* in_sizes, int n_in,
                              void* d_out, int out_size, void* d_ws, size_t ws_size,
                              hipStream_t stream) {
  const float* x    = (const float*)d_in[0];
  const float* W    = (const float*)d_in[1];
  const float* bias = (const float*)d_in[2];
  const float* ln_g = (const float*)d_in[3];
  const float* ln_b = (const float*)d_in[4];
  const float* fc_w = (const float*)d_in[5];
  const float* fc_b = (const float*)d_in[6];
  float* out = (float*)d_out;
  _Float16* wsh = (_Float16*)d_ws;

  _Float16* x_pk = wsh + X_PK_OFF;
  _Float16* hb[2] = {wsh + HB0_OFF, wsh + HB1_OFF};
  _Float16* Wt2  = wsh + WT2_OFF;
  _Float16* z16  = wsh + Z16_OFF;
  float* Abuf  = (float*)(wsh + A_OFF);
  float* Bc    = (float*)(wsh + BC_OFF);
  float* Bn    = (float*)(wsh + BN_OFF);
  float* stats = (float*)(wsh + STATS_OFF);
  float* carC  = (float*)(wsh + CARC_OFF);
  float* carN  = (float*)(wsh + CARN_OFF);
  float* state = (float*)(wsh + STATE_OFF);
  float* fcp   = (float*)(wsh + FCP_OFF);

  pack_w<<<5120, 256, 0, stream>>>(W, Wt2);
  pack_x<<<256, 256, 0, stream>>>(x, x_pk);

  for (int l = 0; l < L; ++l) {
    const _Float16* A_in = (l == 0) ? x_pk : hb[(l - 1) & 1];
    _Float16* h_out = hb[l & 1];
    const _Float16* Wl = Wt2 + ((size_t)(l * 5) << 20);
    for (int c = 0; c < NCHUNK; ++c) {
      int t0 = c * TCH;
      gemm_big<<<640, 512, 0, stream>>>(A_in, Wl, z16, t0);
      stats_kernel<<<4096, 256, 0, stream>>>(z16, bias, ln_g, ln_b, stats, l);
      scan_p1<<<1024, 256, 0, stream>>>(z16, stats, bias, ln_g, ln_b,
                                        Abuf, Bc, Bn, l);
      scan_p2<<<128, 256, 0, stream>>>(Abuf, Bc, Bn, state, carC, carN, l, t0);
      final_kernel<<<4096, 256, 0, stream>>>(z16, stats, bias, ln_g, ln_b,
                                             Abuf, Bc, Bn, carC, carN,
                                             A_in, h_out, out, l, t0);
    }
  }
  fc_part<<<256, 256, 0, stream>>>(out + 8192 + 3 * 32768, fc_w, fcp);
  fc_reduce<<<B, 256, 0, stream>>>(fcp, fc_b, out);
}

// Round 6
// 909.571 us; speedup vs baseline: 10.6486x; 1.2762x over previous
//
#include <hip/hip_runtime.h>
#include <hip/hip_bf16.h>
#include <math.h>

#define H 1024
#define B 32
#define T 256
#define L 4
#define O 256
#define TCH 128        // time chunk
#define NCHUNK 2
#define SEGLEN 16
#define NSEG (TCH / SEGLEN)   // 8

typedef _Float16 half8 __attribute__((ext_vector_type(8)));
typedef _Float16 half4 __attribute__((ext_vector_type(4)));
typedef float f32x4 __attribute__((ext_vector_type(4)));

// ws layout (offsets in halves):
#define X_PK_OFF   0            // 8,388,608 halves (T*32 rows, A-frag f16)
#define HB0_OFF    8388608
#define HB1_OFF    16777216
#define WT2_OFF    25165824     // 20,971,520 halves
#define Z16_OFF    46137344     // 20,971,520 halves (chunk: 4096 rows x 5 x 1024 f16)
#define A_OFF      67108864     // 8,388,608 halves = 4096x1024 f32 (prefix prod of f)
#define BC_OFF     75497472     // 8,388,608 halves (local c-scan)
#define BN_OFF     83886080     // 8,388,608 halves (local n-scan)
#define STATS_OFF  92274688     // 98,304 halves = 4096x12 f32
#define CARC_OFF   92372992     // 524,288 halves = 8x32768 f32
#define CARN_OFF   92897280     // 524,288 halves
#define STATE_OFF  93421568     // 524,288 halves = 2*L*B*H f32
#define FCP_OFF    93945856     // 131,072 halves = 65536 f32
// total ~188 MB

// ---- pack W[l][j][k][n] fp32 -> f16 B-frag layout (verified r1-r4)
__global__ __launch_bounds__(256) void pack_w(const float* __restrict__ W,
                                              _Float16* __restrict__ Wt2) {
  int tile = blockIdx.x;
  int m_idx = tile >> 8;            // 0..19  (= l*5+jj)
  int kt = (tile >> 4) & 15, ntt = tile & 15;
  int l = m_idx / 5, jj = m_idx % 5;
  const float* Wf = W + ((size_t)(l * 6 + jj + 1) << 20);
  _Float16* out = Wt2 + ((size_t)m_idx << 20);
  __shared__ float ts[64][65];
  int k0 = kt * 64, n0 = ntt * 64;
#pragma unroll
  for (int s = 0; s < 16; ++s) {
    int e = threadIdx.x + s * 256;
    int kk = e >> 6, col = e & 63;
    ts[kk][col] = Wf[(size_t)(k0 + kk) * H + n0 + col];
  }
  __syncthreads();
#pragma unroll
  for (int gi = 0; gi < 2; ++gi) {
    int g = threadIdx.x * 2 + gi;   // 0..511
    int l64 = g & 63, ksl = (g >> 6) & 1, ntl = g >> 7;
    int nn = l64 & 15, kh = l64 >> 4;
    half8 tmp;
#pragma unroll
    for (int e = 0; e < 8; ++e)
      tmp[e] = (_Float16)ts[ksl * 32 + kh * 8 + e][ntl * 16 + nn];
    *(half8*)&out[(size_t)((ntt * 4 + ntl) * 32 + kt * 2 + ksl) * 512 + (size_t)l64 * 8] = tmp;
  }
}

// ---- pack x fp32 -> f16 A-frag layout per t (verified r1-r4)
__global__ __launch_bounds__(256) void pack_x(const float* __restrict__ x,
                                              _Float16* __restrict__ x_pk) {
  int t = blockIdx.x;
  __shared__ float ld[32][257];
  for (int c = 0; c < 4; ++c) {
#pragma unroll
    for (int s = 0; s < 32; ++s) {
      int e2 = threadIdx.x + s * 256;
      int b = e2 >> 8, col = e2 & 255;
      ld[b][col] = x[((size_t)b * T + t) * H + c * 256 + col];
    }
    __syncthreads();
#pragma unroll
    for (int s3 = 0; s3 < 4; ++s3) {
      int gg = threadIdx.x * 4 + s3;  // 0..1023
      int l64 = gg & 63, ksl = (gg >> 6) & 7, bt = gg >> 9;
      int nn = l64 & 15, kh = l64 >> 4;
      int b = bt * 16 + nn;
      half8 tmp;
#pragma unroll
      for (int e = 0; e < 8; ++e)
        tmp[e] = (_Float16)ld[b][ksl * 32 + kh * 8 + e];
      *(half8*)&x_pk[(size_t)t * 32768 + (size_t)bt * 16384 +
                     (size_t)(c * 8 + ksl) * 512 + (size_t)l64 * 8] = tmp;
    }
    __syncthreads();
  }
}

// ---- GEMM: block 128m x 256n, 8 waves (2wm x 4wn), wave 64m x 64n.
// LDS double-buffered staging via reg + ds_write (frag-contiguous, conflict-free).
// Per buffer: A 8 frags (4096 halves) + B 16 frags (8192 halves) = 12288 halves.
__global__ __launch_bounds__(512) void gemm_big(
    const _Float16* __restrict__ A_pk, const _Float16* __restrict__ Wl,
    _Float16* __restrict__ z16, int t0) {
  int raw = blockIdx.x;
  int swz = (raw & 7) * 80 + (raw >> 3);   // 640 = 8 XCD x 80, bijective
  int bm = swz & 31;
  int bn = swz >> 5;
  int w = threadIdx.x >> 6, lane = threadIdx.x & 63;
  int wm = w >> 2, wn = w & 3;

  __shared__ _Float16 smem[24576];   // 2 x 12288; epilogue reuses as cz[64][264]

  int j = bn >> 2;
  // this wave's 3 staging frags (24 total: A f=0..7 -> mt, B f=8..23 -> nt)
  const _Float16* gsrc[3];
  int ldst[3];
#pragma unroll
  for (int q = 0; q < 3; ++q) {
    int f = w * 3 + q;
    if (f < 8) {
      gsrc[q] = A_pk + (size_t)(t0 * 2 + bm * 8 + f) * 16384 + lane * 8;
      ldst[q] = f * 512 + lane * 8;
    } else {
      int nf = f - 8;
      gsrc[q] = Wl + ((size_t)j << 20) + (size_t)((bn & 3) * 16 + nf) * 16384 + lane * 8;
      ldst[q] = 4096 + nf * 512 + lane * 8;
    }
  }

  // prologue: stage ks=0 into buffer 0
  half8 st[3];
#pragma unroll
  for (int q = 0; q < 3; ++q) st[q] = *(const half8*)(gsrc[q]);
#pragma unroll
  for (int q = 0; q < 3; ++q) *(half8*)&smem[ldst[q]] = st[q];
  __syncthreads();

  f32x4 acc[4][4] = {};
  int ardo = wm * 4 * 512 + lane * 8;          // a-frag read base (within buffer)
  int brdo = 4096 + wn * 4 * 512 + lane * 8;   // b-frag read base

  for (int ks = 0; ks < 32; ++ks) {
    int cur = (ks & 1) * 12288;
    // prefetch next K-step into regs (overlaps with ds_read+MFMA below)
    if (ks + 1 < 32) {
#pragma unroll
      for (int q = 0; q < 3; ++q) st[q] = *(const half8*)(gsrc[q] + (ks + 1) * 512);
    }
    half8 a[4], b[4];
#pragma unroll
    for (int i = 0; i < 4; ++i) a[i] = *(const half8*)&smem[cur + ardo + i * 512];
#pragma unroll
    for (int i = 0; i < 4; ++i) b[i] = *(const half8*)&smem[cur + brdo + i * 512];
#pragma unroll
    for (int i = 0; i < 4; ++i)
#pragma unroll
      for (int jf = 0; jf < 4; ++jf)
        acc[i][jf] = __builtin_amdgcn_mfma_f32_16x16x32_f16(a[i], b[jf], acc[i][jf], 0, 0, 0);
    __syncthreads();   // all reads of cur^12288's prior contents done
    if (ks + 1 < 32) {
#pragma unroll
      for (int q = 0; q < 3; ++q) *(half8*)&smem[(cur ^ 12288) + ldst[q]] = st[q];
    }
    __syncthreads();   // writes visible before next iter's reads
  }

  // epilogue (verified r3/r4): stage C tile via LDS, store half8 rows
  _Float16 (*cz)[264] = (_Float16(*)[264])smem;
  int hb0 = (bn & 3) * 256;
  for (int p = 0; p < 2; ++p) {
    if (p) __syncthreads();
    if (wm == p) {
#pragma unroll
      for (int i = 0; i < 4; ++i)
#pragma unroll
        for (int jf = 0; jf < 4; ++jf)
#pragma unroll
          for (int r = 0; r < 4; ++r)
            cz[i * 16 + (lane >> 4) * 4 + r][wn * 64 + jf * 16 + (lane & 15)] =
                (_Float16)acc[i][jf][r];
    }
    __syncthreads();
#pragma unroll
    for (int s = 0; s < 4; ++s) {
      int e = threadIdx.x + s * 512;
      int r = e >> 5, h8 = e & 31;
      int m_local = bm * 128 + p * 64 + r;
      half8 vv = *(const half8*)&cz[r][h8 * 8];
      *(half8*)&z16[((size_t)m_local * 5 + j) * 1024 + hb0 + h8 * 8] = vv;
    }
  }
}

// ---- per-row LN stats + ksum (verified r3/r4)
__global__ __launch_bounds__(256) void stats_kernel(
    const _Float16* __restrict__ z16, const float* __restrict__ bias,
    const float* __restrict__ ln_g, const float* __restrict__ ln_b,
    float* __restrict__ stats, int l) {
  int row = blockIdx.x, tid = threadIdx.x;
  int h0 = tid * 4;
  float red[13];
#pragma unroll
  for (int jj = 0; jj < 5; ++jj) {
    half4 z4 = *(const half4*)&z16[((size_t)row * 5 + jj) * 1024 + h0];
    float4 bb = *(const float4*)&bias[(size_t)(l * 6 + 1 + jj) * H + h0];
    float vx = (float)z4[0] + bb.x, vy = (float)z4[1] + bb.y,
          vz = (float)z4[2] + bb.z, vw = (float)z4[3] + bb.w;
    red[jj * 2] = vx + vy + vz + vw;
    red[jj * 2 + 1] = vx * vx + vy * vy + vz * vz + vw * vw;
    if (jj == 0) {
      float4 g = *(const float4*)&ln_g[(size_t)(l * 6 + 1) * H + h0];
      float4 be = *(const float4*)&ln_b[(size_t)(l * 6 + 1) * H + h0];
      red[10] = vx * g.x + vy * g.y + vz * g.z + vw * g.w;
      red[11] = g.x + g.y + g.z + g.w;
      red[12] = be.x + be.y + be.z + be.w;
    }
  }
#pragma unroll
  for (int off = 32; off; off >>= 1)
#pragma unroll
    for (int q = 0; q < 13; ++q) red[q] += __shfl_down(red[q], off);
  __shared__ float sb[4][13];
  if ((tid & 63) == 0) {
#pragma unroll
    for (int q = 0; q < 13; ++q) sb[tid >> 6][q] = red[q];
  }
  __syncthreads();
  if (tid == 0) {
    float st[13];
#pragma unroll
    for (int q = 0; q < 13; ++q) st[q] = sb[0][q] + sb[1][q] + sb[2][q] + sb[3][q];
    float* so = stats + (size_t)row * 12;
#pragma unroll
    for (int jj = 0; jj < 5; ++jj) {
      float mu = st[jj * 2] * (1.0f / H);
      float var = st[jj * 2 + 1] * (1.0f / H) - mu * mu;
      so[jj * 2] = mu;
      so[jj * 2 + 1] = rsqrtf(var + 1e-5f);
    }
    float mu0 = st[0] * (1.0f / H);
    float rs0 = rsqrtf(st[1] * (1.0f / H) - mu0 * mu0 + 1e-5f);
    so[10] = rs0 * (st[10] - mu0 * st[11]) + st[12];
    so[11] = 0.f;
  }
}

// ---- scan pass 1: per-segment local scans (verified r4)
__global__ __launch_bounds__(256) void scan_p1(
    const _Float16* __restrict__ z16, const float* __restrict__ stats,
    const float* __restrict__ bias, const float* __restrict__ ln_g,
    const float* __restrict__ ln_b, float* __restrict__ Abuf,
    float* __restrict__ Bc, float* __restrict__ Bn, int l) {
  int idx = blockIdx.x * 256 + threadIdx.x;   // 262144 threads
  int h = idx & 1023;
  int bs = idx >> 10;
  int b = bs & 31, seg = bs >> 5;

  float bz[4], gg[4], bb[4];
#pragma unroll
  for (int jj = 0; jj < 4; ++jj) {
    bz[jj] = bias[(size_t)(l * 6 + 1 + jj) * H + h];
    gg[jj] = ln_g[(size_t)(l * 6 + 1 + jj) * H + h];
    bb[jj] = ln_b[(size_t)(l * 6 + 1 + jj) * H + h];
  }
  float A = 1.f, bc = 0.f, bn = 0.f;
#pragma unroll 2
  for (int u = 0; u < SEGLEN; ++u) {
    int row = (seg * SEGLEN + u) * 32 + b;
    size_t zb = ((size_t)row * 5) * 1024 + h;
    float zk = (float)z16[zb];
    float zv = (float)z16[zb + 1024];
    float zi = (float)z16[zb + 2048];
    float zf = (float)z16[zb + 3072];
    const float* st = stats + (size_t)row * 12;
    float k   = (zk + bz[0] - st[0]) * st[1] * gg[0] + bb[0];
    float v   = (zv + bz[1] - st[2]) * st[3] * gg[1] + bb[1];
    float zi_ = (zi + bz[2] - st[4]) * st[5] * gg[2] + bb[2];
    float zf_ = (zf + bz[3] - st[6]) * st[7] * gg[3] + bb[3];
    float iv = __expf(zi_);
    float fv = 1.f / (1.f + __expf(-zf_));
    A *= fv;
    bn = fv * bn + iv * k;
    bc = fv * bc + iv * (st[10] * v);
    size_t o = (size_t)row * 1024 + h;
    Abuf[o] = A;
    Bn[o] = bn;
    Bc[o] = bc;
  }
}

// ---- scan pass 2: carry-in per segment (verified r4)
__global__ __launch_bounds__(256) void scan_p2(
    const float* __restrict__ Abuf, const float* __restrict__ Bc,
    const float* __restrict__ Bn, float* __restrict__ state,
    float* __restrict__ carC, float* __restrict__ carN, int l, int t0) {
  int idx = blockIdx.x * 256 + threadIdx.x;   // 32768
  int h = idx & 1023, b = idx >> 10;
  size_t sidx = ((size_t)l * B + b) * H + h;
  float cc = 0.f, nn = 0.f;
  if (t0 > 0) {
    cc = state[sidx];
    nn = state[(size_t)L * B * H + sidx];
  }
#pragma unroll
  for (int seg = 0; seg < NSEG; ++seg) {
    size_t coff = (size_t)seg * 32768 + (size_t)b * 1024 + h;
    carC[coff] = cc;
    carN[coff] = nn;
    int rowLast = (seg * SEGLEN + SEGLEN - 1) * 32 + b;
    size_t o = (size_t)rowLast * 1024 + h;
    float a = Abuf[o];
    cc = Bc[o] + a * cc;
    nn = Bn[o] + a * nn;
  }
  state[sidx] = cc;
  state[(size_t)L * B * H + sidx] = nn;
}

// ---- final (verified r4)
__global__ __launch_bounds__(256) void final_kernel(
    const _Float16* __restrict__ z16, const float* __restrict__ stats,
    const float* __restrict__ bias, const float* __restrict__ ln_g,
    const float* __restrict__ ln_b, const float* __restrict__ Abuf,
    const float* __restrict__ Bc, const float* __restrict__ Bn,
    const float* __restrict__ carC, const float* __restrict__ carN,
    const _Float16* __restrict__ hin, _Float16* __restrict__ hout,
    float* __restrict__ out, int l, int t0) {
  int row = blockIdx.x;
  int b = row & 31, tc = row >> 5, t = t0 + tc, seg = tc / SEGLEN;
  int tid = threadIdx.x, h0 = tid * 4;
  size_t o = (size_t)row * 1024 + h0;
  size_t coff = (size_t)seg * 32768 + (size_t)b * 1024 + h0;
  float4 a4 = *(const float4*)&Abuf[o];
  float4 bn4 = *(const float4*)&Bn[o];
  float4 bc4 = *(const float4*)&Bc[o];
  float4 cN = *(const float4*)&carN[coff];
  float4 cC = *(const float4*)&carC[coff];
  float nn[4] = {bn4.x + a4.x * cN.x, bn4.y + a4.y * cN.y,
                 bn4.z + a4.z * cN.z, bn4.w + a4.w * cN.w};
  float cc[4] = {bc4.x + a4.x * cC.x, bc4.y + a4.y * cC.y,
                 bc4.z + a4.z * cC.z, bc4.w + a4.w * cC.w};

  float ss = nn[0] * nn[0] + nn[1] * nn[1] + nn[2] * nn[2] + nn[3] * nn[3];
#pragma unroll
  for (int off = 32; off; off >>= 1) ss += __shfl_down(ss, off);
  __shared__ float sb[4];
  if ((tid & 63) == 0) sb[tid >> 6] = ss;
  __syncthreads();
  float rn = 1.f / (sqrtf(sb[0] + sb[1] + sb[2] + sb[3]) + 1e-8f);

  half4 zo4 = *(const half4*)&z16[((size_t)row * 5 + 4) * 1024 + h0];
  const float* st = stats + (size_t)row * 12;
  float mu = st[8], rs = st[9];
  float4 bz = *(const float4*)&bias[(size_t)(l * 6 + 5) * H + h0];
  float4 g4 = *(const float4*)&ln_g[(size_t)(l * 6 + 5) * H + h0];
  float4 be4 = *(const float4*)&ln_b[(size_t)(l * 6 + 5) * H + h0];
  float gv[4] = {g4.x, g4.y, g4.z, g4.w};
  float bev[4] = {be4.x, be4.y, be4.z, be4.w};
  float zov[4] = {(float)zo4[0] + bz.x, (float)zo4[1] + bz.y,
                  (float)zo4[2] + bz.z, (float)zo4[3] + bz.w};

  size_t hfoff = (size_t)(b >> 4) * 16384 + (size_t)(h0 >> 5) * 512 +
                 (size_t)((((h0 & 31) >> 3) * 16) + (b & 15)) * 8 + (h0 & 7);
  half4 rin;
  if (l > 0) rin = *(const half4*)&hin[(size_t)t * 32768 + hfoff];

  float hh[4];
#pragma unroll
  for (int u = 0; u < 4; ++u) {
    float ov = 1.f / (1.f + __expf(-((zov[u] - mu) * rs * gv[u] + bev[u])));
    float targ = cc[u] * (nn[u] * rn);
    float e2 = __expf(-2.f * fabsf(targ));
    float th = copysignf((1.f - e2) / (1.f + e2), targ);
    hh[u] = ov * th + ((l > 0) ? (float)rin[u] : 0.f);
  }
  half4 hx;
  hx[0] = (_Float16)hh[0]; hx[1] = (_Float16)hh[1];
  hx[2] = (_Float16)hh[2]; hx[3] = (_Float16)hh[3];
  *(half4*)&hout[(size_t)t * 32768 + hfoff] = hx;

  if (t == T - 1) {
    *(float4*)&out[8192 + (size_t)l * 32768 + (size_t)b * 1024 + h0] =
        make_float4(hh[0], hh[1], hh[2], hh[3]);
    *(float4*)&out[8192 + 131072 + ((size_t)(l * B) + b) * 1024 + h0] =
        make_float4(cc[0], cc[1], cc[2], cc[3]);
    *(float4*)&out[8192 + 262144 + ((size_t)(l * B) + b) * 1024 + h0] =
        make_float4(nn[0], nn[1], nn[2], nn[3]);
  }
}

// ---- fc: split-K partials + reduce (verified r4)
__global__ __launch_bounds__(256) void fc_part(
    const float* __restrict__ out_h, const float* __restrict__ fc_w,
    float* __restrict__ partial) {
  int b = blockIdx.x >> 3, kh = blockIdx.x & 7;
  int o = threadIdx.x;
  const float* hr = out_h + (size_t)b * 1024 + kh * 128;
  const float* wp = fc_w + (size_t)kh * 128 * O + o;
  float acc = 0.f;
#pragma unroll 8
  for (int h = 0; h < 128; ++h)
    acc = fmaf(hr[h], wp[(size_t)h * O], acc);
  partial[((size_t)kh * 32 + b) * O + o] = acc;
}

__global__ __launch_bounds__(256) void fc_reduce(
    const float* __restrict__ partial, const float* __restrict__ fc_b,
    float* __restrict__ out) {
  int b = blockIdx.x, o = threadIdx.x;
  float acc = fc_b[o];
#pragma unroll
  for (int kh = 0; kh < 8; ++kh)
    acc += partial[((size_t)kh * 32 + b) * O + o];
  out[(size_t)b * O + o] = acc;
}

extern "C" void kernel_launch(void* const* d_in, const int* in_sizes, int n_in,
                              void* d_out, int out_size, void* d_ws, size_t ws_size,
                              hipStream_t stream) {
  const float* x    = (const float*)d_in[0];
  const float* W    = (const float*)d_in[1];
  const float* bias = (const float*)d_in[2];
  const float* ln_g = (const float*)d_in[3];
  const float* ln_b = (const float*)d_in[4];
  const float* fc_w = (const float*)d_in[5];
  const float* fc_b = (const float*)d_in[6];
  float* out = (float*)d_out;
  _Float16* wsh = (_Float16*)d_ws;

  _Float16* x_pk = wsh + X_PK_OFF;
  _Float16* hb[2] = {wsh + HB0_OFF, wsh + HB1_OFF};
  _Float16* Wt2  = wsh + WT2_OFF;
  _Float16* z16  = wsh + Z16_OFF;
  float* Abuf  = (float*)(wsh + A_OFF);
  float* Bc    = (float*)(wsh + BC_OFF);
  float* Bn    = (float*)(wsh + BN_OFF);
  float* stats = (float*)(wsh + STATS_OFF);
  float* carC  = (float*)(wsh + CARC_OFF);
  float* carN  = (float*)(wsh + CARN_OFF);
  float* state = (float*)(wsh + STATE_OFF);
  float* fcp   = (float*)(wsh + FCP_OFF);

  pack_w<<<5120, 256, 0, stream>>>(W, Wt2);
  pack_x<<<256, 256, 0, stream>>>(x, x_pk);

  for (int l = 0; l < L; ++l) {
    const _Float16* A_in = (l == 0) ? x_pk : hb[(l - 1) & 1];
    _Float16* h_out = hb[l & 1];
    const _Float16* Wl = Wt2 + ((size_t)(l * 5) << 20);
    for (int c = 0; c < NCHUNK; ++c) {
      int t0 = c * TCH;
      gemm_big<<<640, 512, 0, stream>>>(A_in, Wl, z16, t0);
      stats_kernel<<<4096, 256, 0, stream>>>(z16, bias, ln_g, ln_b, stats, l);
      scan_p1<<<1024, 256, 0, stream>>>(z16, stats, bias, ln_g, ln_b,
                                        Abuf, Bc, Bn, l);
      scan_p2<<<128, 256, 0, stream>>>(Abuf, Bc, Bn, state, carC, carN, l, t0);
      final_kernel<<<4096, 256, 0, stream>>>(z16, stats, bias, ln_g, ln_b,
                                             Abuf, Bc, Bn, carC, carN,
                                             A_in, h_out, out, l, t0);
    }
  }
  fc_part<<<256, 256, 0, stream>>>(out + 8192 + 3 * 32768, fc_w, fcp);
  fc_reduce<<<B, 256, 0, stream>>>(fcp, fc_b, out);
}